// Round 8
// baseline (171.447 us; speedup 1.0000x reference)
//
#include <hip/hip_runtime.h>
#include <hip/hip_bf16.h>

typedef unsigned long long u64;
typedef unsigned int u32;
typedef __attribute__((ext_vector_type(4))) double f64x4;

#define NB   64
#define NPOS 1024
#define NOUT 25
#define NCLS 20
#define WROW 32            // f64 weights per channel row, padded to 256 B

// ---- workspace layout (bytes) ----
#define OFF_W64   0          // double wpad[512*32] = 131072
#define OFF_B64   131072     // double b64[25]      = 200 (pad to 131328)
#define OFF_ORDER 131328     // int    order[64*1024]   = 262144
#define OFF_SBOX  393472     // float4 sbox[64*1024]    = 1048576
#define OFF_SCLS  1442048    // int    scls[64*1024]    = 262144
#define OFF_VALID 1704192    // u64    validW[64*16]    = 8192
#define OFF_MASK  1712384    // u64    masksT[64][16][1024] = 8388608 -> end 10100992

// ---------------- kernel 0: weights -> f64, layout [c][32] (pad 0) -----------
__global__ __launch_bounds__(256) void k_cvt(const float* __restrict__ w,
                                             const float* __restrict__ bias,
                                             double* __restrict__ wpad,
                                             double* __restrict__ b64)
{
    int idx = blockIdx.x * 256 + threadIdx.x;
    if (idx < 512 * WROW) {
        int c = idx >> 5, o = idx & 31;
        wpad[idx] = (o < NOUT) ? (double)w[o * 512 + c] : 0.0;
    }
    if (idx < NOUT) b64[idx] = (double)bias[idx];
}

// ---------------- f64 epilogue: sigmoid/softmax/argmax + box decode ----------
__device__ __forceinline__ void epilogue(const double* __restrict__ acc,
                                         const double* __restrict__ b64,
                                         int n, int gi,
                                         float* __restrict__ boxes_out,
                                         float* __restrict__ scores_out,
                                         float* __restrict__ cls_out)
{
    double p[NOUT];
#pragma unroll
    for (int o = 0; o < NOUT; ++o) p[o] = acc[o] + b64[o];

    double conf = 1.0 / (1.0 + exp(-p[0]));
    // argmax over logits (== argmax of conf*softmax), first-max semantics
    double m = p[1]; int ci = 0;
#pragma unroll
    for (int i = 2; i <= NCLS; ++i) {
        if (p[i] > m) { m = p[i]; ci = i - 1; }
    }
    double ssum = 0.0;
#pragma unroll
    for (int i = 0; i < NCLS; ++i) ssum += exp(p[1 + i] - m);
    double best = conf / ssum;      // == conf * e_top/ssum with e_top = exp(0)

    int gx = n & 31, gy = n >> 5;
    double sx = 1.0 / (1.0 + exp(-p[21]));
    double sy = 1.0 / (1.0 + exp(-p[22]));
    double cx = (sx + (double)gx) * 32.0;
    double cy = (sy + (double)gy) * 32.0;
    double bw = exp(p[23]), bh = exp(p[24]);
    double x1 = (cx - bw * 0.5) * (1.0 / 1024.0);
    double y1 = (cy - bh * 0.5) * (1.0 / 1024.0);
    double x2 = (cx + bw * 0.5) * (1.0 / 1024.0);
    double y2 = (cy + bh * 0.5) * (1.0 / 1024.0);
    x1 = fmin(fmax(x1, 0.0), 1.0); y1 = fmin(fmax(y1, 0.0), 1.0);
    x2 = fmin(fmax(x2, 0.0), 1.0); y2 = fmin(fmax(y2, 0.0), 1.0);

    ((float4*)boxes_out)[gi] = make_float4((float)x1, (float)y1, (float)x2, (float)y2);
    scores_out[gi] = (float)best;
    cls_out[gi]    = (float)ci;
}

// ---------------- kernel 1: f64 MFMA GEMM -----------------------------------
// D[pos16 x out16] = A[pos16 x k4] * B[k4 x out16], K = 512 via 128 steps.
// A lane l: feat[c0 + (l>>4)][n0 + (l&15)]  (f32 load -> cvt f64)
// B lane l: wpad[c0 + (l>>4)][l&15 (+16)]   (f64 vector load, L1/L2-hit)
// D row map for 16x16x4f64 is SELF-CALIBRATED at runtime (one identity MFMA):
// round-7 failure showed it differs from the 16x16x32 convention.
__global__ __launch_bounds__(256, 4) void k_main(const float* __restrict__ feat,
                                                 const double* __restrict__ wpad_g,
                                                 const double* __restrict__ b64,
                                                 float* __restrict__ boxes_out,
                                                 float* __restrict__ scores_out,
                                                 float* __restrict__ cls_out)
{
    __shared__ double pd[64][33];                 // 16896 B, epilogue transpose
    const int b   = blockIdx.y;
    const int tid = threadIdx.x;
    const int l   = tid & 63;
    const int wv  = tid >> 6;
    const int n0  = blockIdx.x * 64 + wv * 16;    // wave's 16-position tile

    // --- runtime D-row calibration: A[m][0]=m, B[0][n]=1 => D[m][n]=m -------
    {
        // (executed once; result used to index the LDS dump below)
    }
    double ca = ((l >> 4) == 0) ? (double)(l & 15) : 0.0;
    double cb = ((l >> 4) == 0) ? 1.0 : 0.0;
    f64x4 cd = {0.0, 0.0, 0.0, 0.0};
    cd = __builtin_amdgcn_mfma_f64_16x16x4f64(ca, cb, cd, 0, 0, 0);
    int rmap[4];
#pragma unroll
    for (int v = 0; v < 4; ++v) {
        int r = (int)(cd[v] + 0.5);
        rmap[v] = (r < 0) ? 0 : (r > 15 ? 15 : r);
    }

    const float* __restrict__ fA =
        feat + ((size_t)b * 512 + (l >> 4)) * NPOS + n0 + (l & 15);
    const double* __restrict__ wB = wpad_g + ((l >> 4) << 5) + (l & 15);

    f64x4 acc0 = {0.0, 0.0, 0.0, 0.0};
    f64x4 acc1 = {0.0, 0.0, 0.0, 0.0};

    // depth-2 software pipeline over 128 K-steps (4 channels each)
    float  aC = fA[0];
    double b0C = wB[0],   b1C = wB[16];
    float  aN = fA[4096];
    double b0N = wB[128], b1N = wB[144];

#pragma unroll 1
    for (int s = 0; s < 128; ++s) {
        int s2 = (s + 2) & 127;                   // wraps: dummy reloads at tail
        float  aP  = fA[(size_t)s2 * 4096];
        double b0P = wB[(size_t)s2 * 128];
        double b1P = wB[(size_t)s2 * 128 + 16];

        double av = (double)aC;
        acc0 = __builtin_amdgcn_mfma_f64_16x16x4f64(av, b0C, acc0, 0, 0, 0);
        acc1 = __builtin_amdgcn_mfma_f64_16x16x4f64(av, b1C, acc1, 0, 0, 0);

        aC = aN;  b0C = b0N; b1C = b1N;
        aN = aP;  b0N = b0P; b1N = b1P;
    }

    // dump D to LDS as [pos][out] using the calibrated row map
#pragma unroll
    for (int v = 0; v < 4; ++v) {
        int pos = wv * 16 + rmap[v];
        pd[pos][(l & 15)]      = acc0[v];
        pd[pos][(l & 15) + 16] = acc1[v];
    }
    __syncthreads();

    if (tid < 64) {
        double acc[NOUT];
#pragma unroll
        for (int o = 0; o < NOUT; ++o) acc[o] = pd[tid][o];
        int n = blockIdx.x * 64 + tid;
        epilogue(acc, b64, n, b * NPOS + n, boxes_out, scores_out, cls_out);
    }
}

// ---------------- kernel 2: per-batch bitonic sort (desc score, stable) -------
__global__ __launch_bounds__(256) void k_sort(const float* __restrict__ scores,
                                              const float* __restrict__ boxes,
                                              const float* __restrict__ cls,
                                              int* __restrict__ order,
                                              float4* __restrict__ sbox,
                                              int* __restrict__ scls,
                                              u64* __restrict__ validW)
{
    __shared__ u64 key[NPOS];
    __shared__ u64 vw[16];
    int b = blockIdx.x, tid = threadIdx.x;

    for (int ppos = tid; ppos < NPOS; ppos += 256) {
        u32 bits = __float_as_uint(scores[b * NPOS + ppos]);
        u32 d = ~(bits | 0x80000000u);   // descending-monotone key (scores >= 0)
        key[ppos] = ((u64)d << 32) | (u32)ppos;
    }
    if (tid < 16) vw[tid] = 0ull;
    __syncthreads();

    for (int k = 2; k <= NPOS; k <<= 1) {
        for (int j = k >> 1; j > 0; j >>= 1) {
            for (int idx = tid; idx < NPOS; idx += 256) {
                int l = idx ^ j;
                if (l > idx) {
                    u64 a = key[idx], c = key[l];
                    bool up = ((idx & k) == 0);
                    if ((a > c) == up) { key[idx] = c; key[l] = a; }
                }
            }
            __syncthreads();
        }
    }

    for (int ppos = tid; ppos < NPOS; ppos += 256) {
        u64 kk = key[ppos];
        int idx = (int)(kk & 0xffffffffu);
        order[b * NPOS + ppos] = idx;
        sbox [b * NPOS + ppos] = ((const float4*)boxes)[b * NPOS + idx];
        scls [b * NPOS + ppos] = (int)cls[b * NPOS + idx];
        u32 sb = (~(u32)(kk >> 32)) & 0x7fffffffu;
        float sc = __uint_as_float(sb);
        if (sc > 0.01f) atomicOr(&vw[ppos >> 6], 1ull << (ppos & 63));
    }
    __syncthreads();
    if (tid < 16) validW[b * 16 + tid] = vw[tid];
}

// ---------------- kernel 3: suppression mask, ballot style -------------------
__global__ __launch_bounds__(64) void k_mask(const float4* __restrict__ sbox,
                                             const int* __restrict__ scls,
                                             u64* __restrict__ masksT)
{
    __shared__ float4 boxl[256];
    __shared__ float2 acl[256];
    const int wc  = blockIdx.x;
    const int w   = wc >> 2, chunk = wc & 3;
    const int b   = blockIdx.y;
    const int lane = threadIdx.x;
    const int i0   = chunk * 256;
    const int imax = (w + 1) * 64;            // rows that can suppress into word w
    u64* __restrict__ mcol = masksT + (((size_t)b * 16 + w) << 10);

    const int jg = w * 64 + lane;
    float4 bj = sbox[b * NPOS + jg];
    float  aj = (bj.z - bj.x) * (bj.w - bj.y);
    int    cj = scls[b * NPOS + jg];

    int iend = imax - i0;                     // rows in this chunk needing compute
    if (iend > 256) iend = 256;

    if (iend > 0) {
        for (int i = lane; i < iend; i += 64) {
            float4 bb = sbox[b * NPOS + i0 + i];
            boxl[i] = bb;
            acl[i]  = make_float2((bb.z - bb.x) * (bb.w - bb.y),
                                  __int_as_float(scls[b * NPOS + i0 + i]));
        }
    }
    __syncthreads();

#pragma unroll 1
    for (int t = 0; t < 256; t += 64) {       // 64-row tiles
        u64 myword = 0ull;
        if (t < iend) {
#pragma unroll 1
            for (int s = 0; s < 64; s += 8) {
                u64 bits[8];
#pragma unroll
                for (int u = 0; u < 8; ++u) {
                    int i = t + s + u;
                    float4 bi = boxl[i];      // wave-uniform broadcast
                    float2 ac = acl[i];
                    float xx1 = fmaxf(bi.x, bj.x), yy1 = fmaxf(bi.y, bj.y);
                    float xx2 = fminf(bi.z, bj.z), yy2 = fminf(bi.w, bj.w);
                    float ww = fmaxf(1e-28f, xx2 - xx1);
                    float hh = fmaxf(1e-28f, yy2 - yy1);
                    float inter = ww * hh;
                    float uni = ac.x + aj - inter;
                    bool sup = (__float_as_int(ac.y) == cj) && (uni > 0.0f) &&
                               (inter > 0.5f * uni) && (jg > i0 + i) && (i < iend);
                    bits[u] = __ballot(sup);
                }
#pragma unroll
                for (int u = 0; u < 8; ++u)
                    myword = (lane == s + u) ? bits[u] : myword;
            }
        }
        mcol[i0 + t + lane] = myword;         // coalesced (row-major in word)
    }
}

// ---------------- kernel 4: sequential suppression scan + scatter keep --------
__global__ __launch_bounds__(64) void k_scan(const u64* __restrict__ validW,
                                             const u64* __restrict__ masksT,
                                             const int* __restrict__ order,
                                             float* __restrict__ keep_out)
{
    int b = blockIdx.x, lane = threadIdx.x;
    u64 keep = (lane < 16) ? validW[b * 16 + lane] : 0ull;
    const u64* M = masksT + ((size_t)b << 14);    // [16 words][1024 rows]
    int myrow = lane >> 4;
    int myw = lane & 15;

    u64 buf[8];
#pragma unroll
    for (int d = 0; d < 8; ++d)
        buf[d] = M[((size_t)myw << 10) + (d * 4 + myrow)];

    for (int g0 = 0; g0 < 256; g0 += 8) {
#pragma unroll
        for (int d = 0; d < 8; ++d) {
            int g = g0 + d;
            u64 cur = buf[d];
            int gp = g + 8;
            buf[d] = (gp < 256) ? M[((size_t)myw << 10) + (gp * 4 + myrow)] : 0ull;
            if (__any(cur != 0ull)) {
#pragma unroll
                for (int r = 0; r < 4; ++r) {
                    int i = g * 4 + r;
                    u64 kw = __shfl(keep, i >> 6);
                    if ((kw >> (i & 63)) & 1ull) {
                        u64 mm = __shfl(cur, r * 16 + myw);
                        if (lane < 16) keep &= ~mm;
                    }
                }
            }
        }
    }

#pragma unroll
    for (int t = 0; t < 16; ++t) {
        int ppos = t * 64 + lane;
        u64 kw = __shfl(keep, t);
        float v = ((kw >> lane) & 1ull) ? 1.0f : 0.0f;
        keep_out[b * NPOS + order[b * NPOS + ppos]] = v;
    }
}

// ------------------------------------------------------------------------------
extern "C" void kernel_launch(void* const* d_in, const int* in_sizes, int n_in,
                              void* d_out, int out_size, void* d_ws, size_t ws_size,
                              hipStream_t stream)
{
    const float* feat = (const float*)d_in[0];
    const float* w    = (const float*)d_in[1];
    const float* bias = (const float*)d_in[2];

    float* out = (float*)d_out;
    float* boxes_out  = out;
    float* scores_out = out + NB * NPOS * 4;
    float* cls_out    = out + NB * NPOS * 5;
    float* keep_out   = out + NB * NPOS * 6;

    char* ws = (char*)d_ws;
    double* wpad  = (double*)(ws + OFF_W64);
    double* b64   = (double*)(ws + OFF_B64);
    int*    order = (int*)   (ws + OFF_ORDER);
    float4* sbox  = (float4*)(ws + OFF_SBOX);
    int*    scls  = (int*)   (ws + OFF_SCLS);
    u64*    validW= (u64*)   (ws + OFF_VALID);
    u64*    masksT= (u64*)   (ws + OFF_MASK);

    hipLaunchKernelGGL(k_cvt,  dim3(64),     dim3(256), 0, stream, w, bias, wpad, b64);
    hipLaunchKernelGGL(k_main, dim3(16, 64), dim3(256), 0, stream, feat, wpad, b64,
                       boxes_out, scores_out, cls_out);
    hipLaunchKernelGGL(k_sort, dim3(64),     dim3(256), 0, stream, scores_out,
                       boxes_out, cls_out, order, sbox, scls, validW);
    hipLaunchKernelGGL(k_mask, dim3(64, 64), dim3(64),  0, stream, sbox, scls, masksT);
    hipLaunchKernelGGL(k_scan, dim3(64),     dim3(64),  0, stream, validW, masksT,
                       order, keep_out);
}

// Round 9
// 165.100 us; speedup vs baseline: 1.0384x; 1.0384x over previous
//
#include <hip/hip_runtime.h>
#include <hip/hip_bf16.h>

typedef unsigned long long u64;
typedef unsigned int u32;
typedef __attribute__((ext_vector_type(4))) double f64x4;

#define NB   64
#define NPOS 1024
#define NOUT 25
#define NCLS 20
#define WROW 32            // f64 weights per channel row, padded to 256 B

// ---- workspace layout (bytes) ----
#define OFF_W64   0          // double wpad[512*32] = 131072
#define OFF_B64   131072     // double b64[25]      = 200 (pad to 131328)
#define OFF_ORDER 131328     // int    order[64*1024]   = 262144
#define OFF_SBOX  393472     // float4 sbox[64*1024]    = 1048576
#define OFF_SCLS  1442048    // int    scls[64*1024]    = 262144
#define OFF_VALID 1704192    // u64    validW[64*16]    = 8192
#define OFF_MASK  1712384    // u64    masksT[64][16][1024] = 8388608 -> end 10100992

// ---------------- kernel 0: weights -> f64, layout [c][32] (pad 0) -----------
__global__ __launch_bounds__(256) void k_cvt(const float* __restrict__ w,
                                             const float* __restrict__ bias,
                                             double* __restrict__ wpad,
                                             double* __restrict__ b64)
{
    int idx = blockIdx.x * 256 + threadIdx.x;
    if (idx < 512 * WROW) {
        int c = idx >> 5, o = idx & 31;
        wpad[idx] = (o < NOUT) ? (double)w[o * 512 + c] : 0.0;
    }
    if (idx < NOUT) b64[idx] = (double)bias[idx];
}

// ---------------- f64 epilogue: sigmoid/softmax/argmax + box decode ----------
__device__ __forceinline__ void epilogue(const double* __restrict__ acc,
                                         const double* __restrict__ b64,
                                         int n, int gi,
                                         float* __restrict__ boxes_out,
                                         float* __restrict__ scores_out,
                                         float* __restrict__ cls_out)
{
    double p[NOUT];
#pragma unroll
    for (int o = 0; o < NOUT; ++o) p[o] = acc[o] + b64[o];

    double conf = 1.0 / (1.0 + exp(-p[0]));
    // argmax over logits (== argmax of conf*softmax), first-max semantics
    double m = p[1]; int ci = 0;
#pragma unroll
    for (int i = 2; i <= NCLS; ++i) {
        if (p[i] > m) { m = p[i]; ci = i - 1; }
    }
    double ssum = 0.0;
#pragma unroll
    for (int i = 0; i < NCLS; ++i) ssum += exp(p[1 + i] - m);
    double best = conf / ssum;      // == conf * e_top/ssum with e_top = exp(0)

    int gx = n & 31, gy = n >> 5;
    double sx = 1.0 / (1.0 + exp(-p[21]));
    double sy = 1.0 / (1.0 + exp(-p[22]));
    double cx = (sx + (double)gx) * 32.0;
    double cy = (sy + (double)gy) * 32.0;
    double bw = exp(p[23]), bh = exp(p[24]);
    double x1 = (cx - bw * 0.5) * (1.0 / 1024.0);
    double y1 = (cy - bh * 0.5) * (1.0 / 1024.0);
    double x2 = (cx + bw * 0.5) * (1.0 / 1024.0);
    double y2 = (cy + bh * 0.5) * (1.0 / 1024.0);
    x1 = fmin(fmax(x1, 0.0), 1.0); y1 = fmin(fmax(y1, 0.0), 1.0);
    x2 = fmin(fmax(x2, 0.0), 1.0); y2 = fmin(fmax(y2, 0.0), 1.0);

    ((float4*)boxes_out)[gi] = make_float4((float)x1, (float)y1, (float)x2, (float)y2);
    scores_out[gi] = (float)best;
    cls_out[gi]    = (float)ci;
}

// ---------------- kernel 1: f64 MFMA GEMM, 32 pos/wave, depth-3 --------------
// Per wave: 2 A-fragments (positions n0..n0+15, n0+16..n0+31) share each
// B-fragment pair -> 4 MFMA per {2 A-load + 2 B-load}. 128 K-steps.
// D row map self-calibrated (round-8-proven).
__global__ __launch_bounds__(256, 4) void k_main(const float* __restrict__ feat,
                                                 const double* __restrict__ wpad_g,
                                                 const double* __restrict__ b64,
                                                 float* __restrict__ boxes_out,
                                                 float* __restrict__ scores_out,
                                                 float* __restrict__ cls_out)
{
    __shared__ double pd[128][33];                // 33792 B, epilogue transpose
    const int b   = blockIdx.y;
    const int tid = threadIdx.x;
    const int l   = tid & 63;
    const int wv  = tid >> 6;
    const int n0  = blockIdx.x * 128 + wv * 32;   // wave's 32-position tile

    // --- runtime D-row calibration: A[m][0]=m, B[0][n]=1 => D[m][n]=m -------
    double ca = ((l >> 4) == 0) ? (double)(l & 15) : 0.0;
    double cb = ((l >> 4) == 0) ? 1.0 : 0.0;
    f64x4 cd = {0.0, 0.0, 0.0, 0.0};
    cd = __builtin_amdgcn_mfma_f64_16x16x4f64(ca, cb, cd, 0, 0, 0);
    int rmap[4];
#pragma unroll
    for (int v = 0; v < 4; ++v) {
        int r = (int)(cd[v] + 0.5);
        rmap[v] = (r < 0) ? 0 : (r > 15 ? 15 : r);
    }

    const float* __restrict__ fA =
        feat + ((size_t)b * 512 + (l >> 4)) * NPOS + n0 + (l & 15);
    const double* __restrict__ wB = wpad_g + ((l >> 4) << 5) + (l & 15);

    f64x4 acc00 = {0.0, 0.0, 0.0, 0.0};   // frag0 x out0-15
    f64x4 acc01 = {0.0, 0.0, 0.0, 0.0};   // frag0 x out16-31
    f64x4 acc10 = {0.0, 0.0, 0.0, 0.0};   // frag1 x out0-15
    f64x4 acc11 = {0.0, 0.0, 0.0, 0.0};   // frag1 x out16-31

    // depth-3 software pipeline over 128 K-steps (4 channels each)
    float  a0[3], a1[3];
    double bb0[3], bb1[3];
#pragma unroll
    for (int d = 0; d < 3; ++d) {
        a0[d]  = fA[(size_t)d * 4096];
        a1[d]  = fA[(size_t)d * 4096 + 16];
        bb0[d] = wB[(size_t)d * 128];
        bb1[d] = wB[(size_t)d * 128 + 16];
    }

#pragma unroll 1
    for (int s = 0; s < 128; ++s) {
        int sp = (s + 3) & 127;                   // wraps: dummy reloads at tail
        float  aP0 = fA[(size_t)sp * 4096];
        float  aP1 = fA[(size_t)sp * 4096 + 16];
        double bP0 = wB[(size_t)sp * 128];
        double bP1 = wB[(size_t)sp * 128 + 16];

        int cur = 0;   // rotate via register copies (compile-time unrolled below)
        double av0 = (double)a0[0];
        double av1 = (double)a1[0];
        acc00 = __builtin_amdgcn_mfma_f64_16x16x4f64(av0, bb0[0], acc00, 0, 0, 0);
        acc01 = __builtin_amdgcn_mfma_f64_16x16x4f64(av0, bb1[0], acc01, 0, 0, 0);
        acc10 = __builtin_amdgcn_mfma_f64_16x16x4f64(av1, bb0[0], acc10, 0, 0, 0);
        acc11 = __builtin_amdgcn_mfma_f64_16x16x4f64(av1, bb1[0], acc11, 0, 0, 0);
        (void)cur;

        a0[0] = a0[1];  a0[1] = a0[2];  a0[2] = aP0;
        a1[0] = a1[1];  a1[1] = a1[2];  a1[2] = aP1;
        bb0[0] = bb0[1]; bb0[1] = bb0[2]; bb0[2] = bP0;
        bb1[0] = bb1[1]; bb1[1] = bb1[2]; bb1[2] = bP1;
    }

    // dump D to LDS as [pos][out] using the calibrated row map
#pragma unroll
    for (int v = 0; v < 4; ++v) {
        int p0 = wv * 32 + rmap[v];
        pd[p0][(l & 15)]           = acc00[v];
        pd[p0][(l & 15) + 16]      = acc01[v];
        pd[p0 + 16][(l & 15)]      = acc10[v];
        pd[p0 + 16][(l & 15) + 16] = acc11[v];
    }
    __syncthreads();

    if (tid < 128) {
        double acc[NOUT];
#pragma unroll
        for (int o = 0; o < NOUT; ++o) acc[o] = pd[tid][o];
        int n = blockIdx.x * 128 + tid;
        epilogue(acc, b64, n, b * NPOS + n, boxes_out, scores_out, cls_out);
    }
}

// ---------------- kernel 2: per-batch bitonic sort (desc score, stable) -------
__global__ __launch_bounds__(256) void k_sort(const float* __restrict__ scores,
                                              const float* __restrict__ boxes,
                                              const float* __restrict__ cls,
                                              int* __restrict__ order,
                                              float4* __restrict__ sbox,
                                              int* __restrict__ scls,
                                              u64* __restrict__ validW)
{
    __shared__ u64 key[NPOS];
    __shared__ u64 vw[16];
    int b = blockIdx.x, tid = threadIdx.x;

    for (int ppos = tid; ppos < NPOS; ppos += 256) {
        u32 bits = __float_as_uint(scores[b * NPOS + ppos]);
        u32 d = ~(bits | 0x80000000u);   // descending-monotone key (scores >= 0)
        key[ppos] = ((u64)d << 32) | (u32)ppos;
    }
    if (tid < 16) vw[tid] = 0ull;
    __syncthreads();

    for (int k = 2; k <= NPOS; k <<= 1) {
        for (int j = k >> 1; j > 0; j >>= 1) {
            for (int idx = tid; idx < NPOS; idx += 256) {
                int l = idx ^ j;
                if (l > idx) {
                    u64 a = key[idx], c = key[l];
                    bool up = ((idx & k) == 0);
                    if ((a > c) == up) { key[idx] = c; key[l] = a; }
                }
            }
            __syncthreads();
        }
    }

    for (int ppos = tid; ppos < NPOS; ppos += 256) {
        u64 kk = key[ppos];
        int idx = (int)(kk & 0xffffffffu);
        order[b * NPOS + ppos] = idx;
        sbox [b * NPOS + ppos] = ((const float4*)boxes)[b * NPOS + idx];
        scls [b * NPOS + ppos] = (int)cls[b * NPOS + idx];
        u32 sb = (~(u32)(kk >> 32)) & 0x7fffffffu;
        float sc = __uint_as_float(sb);
        if (sc > 0.01f) atomicOr(&vw[ppos >> 6], 1ull << (ppos & 63));
    }
    __syncthreads();
    if (tid < 16) validW[b * 16 + tid] = vw[tid];
}

// ---------------- kernel 3: suppression mask, ballot style -------------------
__global__ __launch_bounds__(64) void k_mask(const float4* __restrict__ sbox,
                                             const int* __restrict__ scls,
                                             u64* __restrict__ masksT)
{
    __shared__ float4 boxl[256];
    __shared__ float2 acl[256];
    const int wc  = blockIdx.x;
    const int w   = wc >> 2, chunk = wc & 3;
    const int b   = blockIdx.y;
    const int lane = threadIdx.x;
    const int i0   = chunk * 256;
    const int imax = (w + 1) * 64;            // rows that can suppress into word w
    u64* __restrict__ mcol = masksT + (((size_t)b * 16 + w) << 10);

    const int jg = w * 64 + lane;
    float4 bj = sbox[b * NPOS + jg];
    float  aj = (bj.z - bj.x) * (bj.w - bj.y);
    int    cj = scls[b * NPOS + jg];

    int iend = imax - i0;                     // rows in this chunk needing compute
    if (iend > 256) iend = 256;

    if (iend > 0) {
        for (int i = lane; i < iend; i += 64) {
            float4 bb = sbox[b * NPOS + i0 + i];
            boxl[i] = bb;
            acl[i]  = make_float2((bb.z - bb.x) * (bb.w - bb.y),
                                  __int_as_float(scls[b * NPOS + i0 + i]));
        }
    }
    __syncthreads();

#pragma unroll 1
    for (int t = 0; t < 256; t += 64) {       // 64-row tiles
        u64 myword = 0ull;
        if (t < iend) {
#pragma unroll 1
            for (int s = 0; s < 64; s += 8) {
                u64 bits[8];
#pragma unroll
                for (int u = 0; u < 8; ++u) {
                    int i = t + s + u;
                    float4 bi = boxl[i];      // wave-uniform broadcast
                    float2 ac = acl[i];
                    float xx1 = fmaxf(bi.x, bj.x), yy1 = fmaxf(bi.y, bj.y);
                    float xx2 = fminf(bi.z, bj.z), yy2 = fminf(bi.w, bj.w);
                    float ww = fmaxf(1e-28f, xx2 - xx1);
                    float hh = fmaxf(1e-28f, yy2 - yy1);
                    float inter = ww * hh;
                    float uni = ac.x + aj - inter;
                    bool sup = (__float_as_int(ac.y) == cj) && (uni > 0.0f) &&
                               (inter > 0.5f * uni) && (jg > i0 + i) && (i < iend);
                    bits[u] = __ballot(sup);
                }
#pragma unroll
                for (int u = 0; u < 8; ++u)
                    myword = (lane == s + u) ? bits[u] : myword;
            }
        }
        mcol[i0 + t + lane] = myword;         // coalesced (row-major in word)
    }
}

// ---------------- kernel 4: sequential suppression scan + scatter keep --------
__global__ __launch_bounds__(64) void k_scan(const u64* __restrict__ validW,
                                             const u64* __restrict__ masksT,
                                             const int* __restrict__ order,
                                             float* __restrict__ keep_out)
{
    int b = blockIdx.x, lane = threadIdx.x;
    u64 keep = (lane < 16) ? validW[b * 16 + lane] : 0ull;
    const u64* M = masksT + ((size_t)b << 14);    // [16 words][1024 rows]
    int myrow = lane >> 4;
    int myw = lane & 15;

    u64 buf[8];
#pragma unroll
    for (int d = 0; d < 8; ++d)
        buf[d] = M[((size_t)myw << 10) + (d * 4 + myrow)];

    for (int g0 = 0; g0 < 256; g0 += 8) {
#pragma unroll
        for (int d = 0; d < 8; ++d) {
            int g = g0 + d;
            u64 cur = buf[d];
            int gp = g + 8;
            buf[d] = (gp < 256) ? M[((size_t)myw << 10) + (gp * 4 + myrow)] : 0ull;
            if (__any(cur != 0ull)) {
#pragma unroll
                for (int r = 0; r < 4; ++r) {
                    int i = g * 4 + r;
                    u64 kw = __shfl(keep, i >> 6);
                    if ((kw >> (i & 63)) & 1ull) {
                        u64 mm = __shfl(cur, r * 16 + myw);
                        if (lane < 16) keep &= ~mm;
                    }
                }
            }
        }
    }

#pragma unroll
    for (int t = 0; t < 16; ++t) {
        int ppos = t * 64 + lane;
        u64 kw = __shfl(keep, t);
        float v = ((kw >> lane) & 1ull) ? 1.0f : 0.0f;
        keep_out[b * NPOS + order[b * NPOS + ppos]] = v;
    }
}

// ------------------------------------------------------------------------------
extern "C" void kernel_launch(void* const* d_in, const int* in_sizes, int n_in,
                              void* d_out, int out_size, void* d_ws, size_t ws_size,
                              hipStream_t stream)
{
    const float* feat = (const float*)d_in[0];
    const float* w    = (const float*)d_in[1];
    const float* bias = (const float*)d_in[2];

    float* out = (float*)d_out;
    float* boxes_out  = out;
    float* scores_out = out + NB * NPOS * 4;
    float* cls_out    = out + NB * NPOS * 5;
    float* keep_out   = out + NB * NPOS * 6;

    char* ws = (char*)d_ws;
    double* wpad  = (double*)(ws + OFF_W64);
    double* b64   = (double*)(ws + OFF_B64);
    int*    order = (int*)   (ws + OFF_ORDER);
    float4* sbox  = (float4*)(ws + OFF_SBOX);
    int*    scls  = (int*)   (ws + OFF_SCLS);
    u64*    validW= (u64*)   (ws + OFF_VALID);
    u64*    masksT= (u64*)   (ws + OFF_MASK);

    hipLaunchKernelGGL(k_cvt,  dim3(64),     dim3(256), 0, stream, w, bias, wpad, b64);
    hipLaunchKernelGGL(k_main, dim3(8, 64),  dim3(256), 0, stream, feat, wpad, b64,
                       boxes_out, scores_out, cls_out);
    hipLaunchKernelGGL(k_sort, dim3(64),     dim3(256), 0, stream, scores_out,
                       boxes_out, cls_out, order, sbox, scls, validW);
    hipLaunchKernelGGL(k_mask, dim3(64, 64), dim3(64),  0, stream, sbox, scls, masksT);
    hipLaunchKernelGGL(k_scan, dim3(64),     dim3(64),  0, stream, validW, masksT,
                       order, keep_out);
}

// Round 10
// 156.762 us; speedup vs baseline: 1.0937x; 1.0532x over previous
//
#include <hip/hip_runtime.h>
#include <hip/hip_bf16.h>

typedef unsigned long long u64;
typedef unsigned int u32;
typedef __attribute__((ext_vector_type(4))) double f64x4;

#define NB   64
#define NPOS 1024
#define NOUT 25
#define NCLS 20
#define WROW 32            // f64 weights per channel row, padded to 256 B

// ---- workspace layout (bytes) ----
#define OFF_W64   0          // double wpad[512*32] = 131072
#define OFF_B64   131072     // double b64[25]      = 200 (pad to 131328)
#define OFF_ORDER 131328     // int    order[64*1024]   = 262144
#define OFF_SBOX  393472     // float4 sbox[64*1024]    = 1048576
#define OFF_SCLS  1442048    // int    scls[64*1024]    = 262144
#define OFF_VALID 1704192    // u64    validW[64*16]    = 8192
#define OFF_MASK  1712384    // u64    masksT[64][16][1024] = 8388608 -> end 10100992

// ---------------- kernel 0: weights -> f64, layout [c][32] (pad 0) -----------
__global__ __launch_bounds__(256) void k_cvt(const float* __restrict__ w,
                                             const float* __restrict__ bias,
                                             double* __restrict__ wpad,
                                             double* __restrict__ b64)
{
    int idx = blockIdx.x * 256 + threadIdx.x;
    if (idx < 512 * WROW) {
        int c = idx >> 5, o = idx & 31;
        wpad[idx] = (o < NOUT) ? (double)w[o * 512 + c] : 0.0;
    }
    if (idx < NOUT) b64[idx] = (double)bias[idx];
}

// ---------------- f64 epilogue: sigmoid/softmax/argmax + box decode ----------
__device__ __forceinline__ void epilogue(const double* __restrict__ acc,
                                         const double* __restrict__ b64,
                                         int n, int gi,
                                         float* __restrict__ boxes_out,
                                         float* __restrict__ scores_out,
                                         float* __restrict__ cls_out)
{
    double p[NOUT];
#pragma unroll
    for (int o = 0; o < NOUT; ++o) p[o] = acc[o] + b64[o];

    double conf = 1.0 / (1.0 + exp(-p[0]));
    // argmax over logits (== argmax of conf*softmax), first-max semantics
    double m = p[1]; int ci = 0;
#pragma unroll
    for (int i = 2; i <= NCLS; ++i) {
        if (p[i] > m) { m = p[i]; ci = i - 1; }
    }
    double ssum = 0.0;
#pragma unroll
    for (int i = 0; i < NCLS; ++i) ssum += exp(p[1 + i] - m);
    double best = conf / ssum;      // == conf * e_top/ssum with e_top = exp(0)

    int gx = n & 31, gy = n >> 5;
    double sx = 1.0 / (1.0 + exp(-p[21]));
    double sy = 1.0 / (1.0 + exp(-p[22]));
    double cx = (sx + (double)gx) * 32.0;
    double cy = (sy + (double)gy) * 32.0;
    double bw = exp(p[23]), bh = exp(p[24]);
    double x1 = (cx - bw * 0.5) * (1.0 / 1024.0);
    double y1 = (cy - bh * 0.5) * (1.0 / 1024.0);
    double x2 = (cx + bw * 0.5) * (1.0 / 1024.0);
    double y2 = (cy + bh * 0.5) * (1.0 / 1024.0);
    x1 = fmin(fmax(x1, 0.0), 1.0); y1 = fmin(fmax(y1, 0.0), 1.0);
    x2 = fmin(fmax(x2, 0.0), 1.0); y2 = fmin(fmax(y2, 0.0), 1.0);

    ((float4*)boxes_out)[gi] = make_float4((float)x1, (float)y1, (float)x2, (float)y2);
    scores_out[gi] = (float)best;
    cls_out[gi]    = (float)ci;
}

// ---------------- kernel 1: f64 MFMA GEMM, 32 pos/wave, static 8-slot pipe ---
// Per wave: 2 A-fragments share each B-fragment pair -> 4 MFMA per
// {2 A-load + 2 B-load}. 128 K-steps. Circular buffer of 8 slots with
// compile-time indices (unroll 8): NO register rotation, no per-iter
// vmcnt(0) drain; prefetch lead = 5 steps (~1280 cyc of MFMA issue).
// D row map self-calibrated (round-8-proven).
__global__ __launch_bounds__(256, 4) void k_main(const float* __restrict__ feat,
                                                 const double* __restrict__ wpad_g,
                                                 const double* __restrict__ b64,
                                                 float* __restrict__ boxes_out,
                                                 float* __restrict__ scores_out,
                                                 float* __restrict__ cls_out)
{
    __shared__ double pd[128][33];                // 33792 B, epilogue transpose
    const int b   = blockIdx.y;
    const int tid = threadIdx.x;
    const int l   = tid & 63;
    const int wv  = tid >> 6;
    const int n0  = blockIdx.x * 128 + wv * 32;   // wave's 32-position tile

    // --- runtime D-row calibration: A[m][0]=m, B[0][n]=1 => D[m][n]=m -------
    double ca = ((l >> 4) == 0) ? (double)(l & 15) : 0.0;
    double cb = ((l >> 4) == 0) ? 1.0 : 0.0;
    f64x4 cd = {0.0, 0.0, 0.0, 0.0};
    cd = __builtin_amdgcn_mfma_f64_16x16x4f64(ca, cb, cd, 0, 0, 0);
    int rmap[4];
#pragma unroll
    for (int v = 0; v < 4; ++v) {
        int r = (int)(cd[v] + 0.5);
        rmap[v] = (r < 0) ? 0 : (r > 15 ? 15 : r);
    }

    const float* __restrict__ fA =
        feat + ((size_t)b * 512 + (l >> 4)) * NPOS + n0 + (l & 15);
    const double* __restrict__ wB = wpad_g + ((l >> 4) << 5) + (l & 15);

    f64x4 acc00 = {0.0, 0.0, 0.0, 0.0};   // frag0 x out0-15
    f64x4 acc01 = {0.0, 0.0, 0.0, 0.0};   // frag0 x out16-31
    f64x4 acc10 = {0.0, 0.0, 0.0, 0.0};   // frag1 x out0-15
    f64x4 acc11 = {0.0, 0.0, 0.0, 0.0};   // frag1 x out16-31

    // 8-slot circular buffers, all indices compile-time after unroll 8
    float  af0[8], af1[8];
    double bf0[8], bf1[8];
#pragma unroll
    for (int d = 0; d < 5; ++d) {                 // prologue: steps 0..4
        af0[d] = fA[(size_t)d * 4096];
        af1[d] = fA[(size_t)d * 4096 + 16];
        bf0[d] = wB[(size_t)d * 128];
        bf1[d] = wB[(size_t)d * 128 + 16];
    }

#pragma unroll 8
    for (int s = 0; s < 128; ++s) {
        const int slot  = s & 7;
        const int pslot = (s + 5) & 7;
        const int sp    = (s + 5) & 127;          // wraps at tail (dummy reloads)
        af0[pslot] = fA[(size_t)sp * 4096];
        af1[pslot] = fA[(size_t)sp * 4096 + 16];
        bf0[pslot] = wB[(size_t)sp * 128];
        bf1[pslot] = wB[(size_t)sp * 128 + 16];

        double av0 = (double)af0[slot];
        double av1 = (double)af1[slot];
        acc00 = __builtin_amdgcn_mfma_f64_16x16x4f64(av0, bf0[slot], acc00, 0, 0, 0);
        acc01 = __builtin_amdgcn_mfma_f64_16x16x4f64(av0, bf1[slot], acc01, 0, 0, 0);
        acc10 = __builtin_amdgcn_mfma_f64_16x16x4f64(av1, bf0[slot], acc10, 0, 0, 0);
        acc11 = __builtin_amdgcn_mfma_f64_16x16x4f64(av1, bf1[slot], acc11, 0, 0, 0);
    }

    // dump D to LDS as [pos][out] using the calibrated row map
#pragma unroll
    for (int v = 0; v < 4; ++v) {
        int p0 = wv * 32 + rmap[v];
        pd[p0][(l & 15)]           = acc00[v];
        pd[p0][(l & 15) + 16]      = acc01[v];
        pd[p0 + 16][(l & 15)]      = acc10[v];
        pd[p0 + 16][(l & 15) + 16] = acc11[v];
    }
    __syncthreads();

    if (tid < 128) {
        double acc[NOUT];
#pragma unroll
        for (int o = 0; o < NOUT; ++o) acc[o] = pd[tid][o];
        int n = blockIdx.x * 128 + tid;
        epilogue(acc, b64, n, b * NPOS + n, boxes_out, scores_out, cls_out);
    }
}

// ---------------- kernel 2: per-batch bitonic sort (desc score, stable) -------
__global__ __launch_bounds__(256) void k_sort(const float* __restrict__ scores,
                                              const float* __restrict__ boxes,
                                              const float* __restrict__ cls,
                                              int* __restrict__ order,
                                              float4* __restrict__ sbox,
                                              int* __restrict__ scls,
                                              u64* __restrict__ validW)
{
    __shared__ u64 key[NPOS];
    __shared__ u64 vw[16];
    int b = blockIdx.x, tid = threadIdx.x;

    for (int ppos = tid; ppos < NPOS; ppos += 256) {
        u32 bits = __float_as_uint(scores[b * NPOS + ppos]);
        u32 d = ~(bits | 0x80000000u);   // descending-monotone key (scores >= 0)
        key[ppos] = ((u64)d << 32) | (u32)ppos;
    }
    if (tid < 16) vw[tid] = 0ull;
    __syncthreads();

    for (int k = 2; k <= NPOS; k <<= 1) {
        for (int j = k >> 1; j > 0; j >>= 1) {
            for (int idx = tid; idx < NPOS; idx += 256) {
                int l = idx ^ j;
                if (l > idx) {
                    u64 a = key[idx], c = key[l];
                    bool up = ((idx & k) == 0);
                    if ((a > c) == up) { key[idx] = c; key[l] = a; }
                }
            }
            __syncthreads();
        }
    }

    for (int ppos = tid; ppos < NPOS; ppos += 256) {
        u64 kk = key[ppos];
        int idx = (int)(kk & 0xffffffffu);
        order[b * NPOS + ppos] = idx;
        sbox [b * NPOS + ppos] = ((const float4*)boxes)[b * NPOS + idx];
        scls [b * NPOS + ppos] = (int)cls[b * NPOS + idx];
        u32 sb = (~(u32)(kk >> 32)) & 0x7fffffffu;
        float sc = __uint_as_float(sb);
        if (sc > 0.01f) atomicOr(&vw[ppos >> 6], 1ull << (ppos & 63));
    }
    __syncthreads();
    if (tid < 16) validW[b * 16 + tid] = vw[tid];
}

// ---------------- kernel 3: suppression mask, ballot style -------------------
__global__ __launch_bounds__(64) void k_mask(const float4* __restrict__ sbox,
                                             const int* __restrict__ scls,
                                             u64* __restrict__ masksT)
{
    __shared__ float4 boxl[256];
    __shared__ float2 acl[256];
    const int wc  = blockIdx.x;
    const int w   = wc >> 2, chunk = wc & 3;
    const int b   = blockIdx.y;
    const int lane = threadIdx.x;
    const int i0   = chunk * 256;
    const int imax = (w + 1) * 64;            // rows that can suppress into word w
    u64* __restrict__ mcol = masksT + (((size_t)b * 16 + w) << 10);

    const int jg = w * 64 + lane;
    float4 bj = sbox[b * NPOS + jg];
    float  aj = (bj.z - bj.x) * (bj.w - bj.y);
    int    cj = scls[b * NPOS + jg];

    int iend = imax - i0;                     // rows in this chunk needing compute
    if (iend > 256) iend = 256;

    if (iend > 0) {
        for (int i = lane; i < iend; i += 64) {
            float4 bb = sbox[b * NPOS + i0 + i];
            boxl[i] = bb;
            acl[i]  = make_float2((bb.z - bb.x) * (bb.w - bb.y),
                                  __int_as_float(scls[b * NPOS + i0 + i]));
        }
    }
    __syncthreads();

#pragma unroll 1
    for (int t = 0; t < 256; t += 64) {       // 64-row tiles
        u64 myword = 0ull;
        if (t < iend) {
#pragma unroll 1
            for (int s = 0; s < 64; s += 8) {
                u64 bits[8];
#pragma unroll
                for (int u = 0; u < 8; ++u) {
                    int i = t + s + u;
                    float4 bi = boxl[i];      // wave-uniform broadcast
                    float2 ac = acl[i];
                    float xx1 = fmaxf(bi.x, bj.x), yy1 = fmaxf(bi.y, bj.y);
                    float xx2 = fminf(bi.z, bj.z), yy2 = fminf(bi.w, bj.w);
                    float ww = fmaxf(1e-28f, xx2 - xx1);
                    float hh = fmaxf(1e-28f, yy2 - yy1);
                    float inter = ww * hh;
                    float uni = ac.x + aj - inter;
                    bool sup = (__float_as_int(ac.y) == cj) && (uni > 0.0f) &&
                               (inter > 0.5f * uni) && (jg > i0 + i) && (i < iend);
                    bits[u] = __ballot(sup);
                }
#pragma unroll
                for (int u = 0; u < 8; ++u)
                    myword = (lane == s + u) ? bits[u] : myword;
            }
        }
        mcol[i0 + t + lane] = myword;         // coalesced (row-major in word)
    }
}

// ---------------- kernel 4: sequential suppression scan + scatter keep --------
__global__ __launch_bounds__(64) void k_scan(const u64* __restrict__ validW,
                                             const u64* __restrict__ masksT,
                                             const int* __restrict__ order,
                                             float* __restrict__ keep_out)
{
    int b = blockIdx.x, lane = threadIdx.x;
    u64 keep = (lane < 16) ? validW[b * 16 + lane] : 0ull;
    const u64* M = masksT + ((size_t)b << 14);    // [16 words][1024 rows]
    int myrow = lane >> 4;
    int myw = lane & 15;

    u64 buf[8];
#pragma unroll
    for (int d = 0; d < 8; ++d)
        buf[d] = M[((size_t)myw << 10) + (d * 4 + myrow)];

    for (int g0 = 0; g0 < 256; g0 += 8) {
#pragma unroll
        for (int d = 0; d < 8; ++d) {
            int g = g0 + d;
            u64 cur = buf[d];
            int gp = g + 8;
            buf[d] = (gp < 256) ? M[((size_t)myw << 10) + (gp * 4 + myrow)] : 0ull;
            if (__any(cur != 0ull)) {
#pragma unroll
                for (int r = 0; r < 4; ++r) {
                    int i = g * 4 + r;
                    u64 kw = __shfl(keep, i >> 6);
                    if ((kw >> (i & 63)) & 1ull) {
                        u64 mm = __shfl(cur, r * 16 + myw);
                        if (lane < 16) keep &= ~mm;
                    }
                }
            }
        }
    }

#pragma unroll
    for (int t = 0; t < 16; ++t) {
        int ppos = t * 64 + lane;
        u64 kw = __shfl(keep, t);
        float v = ((kw >> lane) & 1ull) ? 1.0f : 0.0f;
        keep_out[b * NPOS + order[b * NPOS + ppos]] = v;
    }
}

// ------------------------------------------------------------------------------
extern "C" void kernel_launch(void* const* d_in, const int* in_sizes, int n_in,
                              void* d_out, int out_size, void* d_ws, size_t ws_size,
                              hipStream_t stream)
{
    const float* feat = (const float*)d_in[0];
    const float* w    = (const float*)d_in[1];
    const float* bias = (const float*)d_in[2];

    float* out = (float*)d_out;
    float* boxes_out  = out;
    float* scores_out = out + NB * NPOS * 4;
    float* cls_out    = out + NB * NPOS * 5;
    float* keep_out   = out + NB * NPOS * 6;

    char* ws = (char*)d_ws;
    double* wpad  = (double*)(ws + OFF_W64);
    double* b64   = (double*)(ws + OFF_B64);
    int*    order = (int*)   (ws + OFF_ORDER);
    float4* sbox  = (float4*)(ws + OFF_SBOX);
    int*    scls  = (int*)   (ws + OFF_SCLS);
    u64*    validW= (u64*)   (ws + OFF_VALID);
    u64*    masksT= (u64*)   (ws + OFF_MASK);

    hipLaunchKernelGGL(k_cvt,  dim3(64),     dim3(256), 0, stream, w, bias, wpad, b64);
    hipLaunchKernelGGL(k_main, dim3(8, 64),  dim3(256), 0, stream, feat, wpad, b64,
                       boxes_out, scores_out, cls_out);
    hipLaunchKernelGGL(k_sort, dim3(64),     dim3(256), 0, stream, scores_out,
                       boxes_out, cls_out, order, sbox, scls, validW);
    hipLaunchKernelGGL(k_mask, dim3(64, 64), dim3(64),  0, stream, sbox, scls, masksT);
    hipLaunchKernelGGL(k_scan, dim3(64),     dim3(64),  0, stream, validW, masksT,
                       order, keep_out);
}

// Round 11
// 155.062 us; speedup vs baseline: 1.1057x; 1.0110x over previous
//
#include <hip/hip_runtime.h>
#include <hip/hip_bf16.h>

typedef unsigned long long u64;
typedef unsigned int u32;
typedef __attribute__((ext_vector_type(4))) double f64x4;

#define NB   64
#define NPOS 1024
#define NOUT 25
#define NCLS 20
#define WROW 32            // f64 weights per channel row, padded to 256 B

// ---- workspace layout (bytes) ----
#define OFF_W64   0          // double wpad[512*32] = 131072
#define OFF_B64   131072     // double b64[25]      = 200 (pad to 131328)
#define OFF_ORDER 131328     // int    order[64*1024]   = 262144
#define OFF_SBOX  393472     // float4 sbox[64*1024]    = 1048576
#define OFF_SCLS  1442048    // int    scls[64*1024]    = 262144
#define OFF_VALID 1704192    // u64    validW[64*16]    = 8192
#define OFF_MASK  1712384    // u64    masksT[64][16][1024] = 8388608 -> end 10100992

// ---------------- kernel 0: weights -> f64, layout [c][32] (pad 0) -----------
__global__ __launch_bounds__(256) void k_cvt(const float* __restrict__ w,
                                             const float* __restrict__ bias,
                                             double* __restrict__ wpad,
                                             double* __restrict__ b64)
{
    int idx = blockIdx.x * 256 + threadIdx.x;
    if (idx < 512 * WROW) {
        int c = idx >> 5, o = idx & 31;
        wpad[idx] = (o < NOUT) ? (double)w[o * 512 + c] : 0.0;
    }
    if (idx < NOUT) b64[idx] = (double)bias[idx];
}

// ---------------- f64 epilogue: sigmoid/softmax/argmax + box decode ----------
__device__ __forceinline__ void epilogue(const double* __restrict__ acc,
                                         const double* __restrict__ b64,
                                         int n, int gi,
                                         float* __restrict__ boxes_out,
                                         float* __restrict__ scores_out,
                                         float* __restrict__ cls_out)
{
    double p[NOUT];
#pragma unroll
    for (int o = 0; o < NOUT; ++o) p[o] = acc[o] + b64[o];

    double conf = 1.0 / (1.0 + exp(-p[0]));
    // argmax over logits (== argmax of conf*softmax), first-max semantics
    double m = p[1]; int ci = 0;
#pragma unroll
    for (int i = 2; i <= NCLS; ++i) {
        if (p[i] > m) { m = p[i]; ci = i - 1; }
    }
    double ssum = 0.0;
#pragma unroll
    for (int i = 0; i < NCLS; ++i) ssum += exp(p[1 + i] - m);
    double best = conf / ssum;      // == conf * e_top/ssum with e_top = exp(0)

    int gx = n & 31, gy = n >> 5;
    double sx = 1.0 / (1.0 + exp(-p[21]));
    double sy = 1.0 / (1.0 + exp(-p[22]));
    double cx = (sx + (double)gx) * 32.0;
    double cy = (sy + (double)gy) * 32.0;
    double bw = exp(p[23]), bh = exp(p[24]);
    double x1 = (cx - bw * 0.5) * (1.0 / 1024.0);
    double y1 = (cy - bh * 0.5) * (1.0 / 1024.0);
    double x2 = (cx + bw * 0.5) * (1.0 / 1024.0);
    double y2 = (cy + bh * 0.5) * (1.0 / 1024.0);
    x1 = fmin(fmax(x1, 0.0), 1.0); y1 = fmin(fmax(y1, 0.0), 1.0);
    x2 = fmin(fmax(x2, 0.0), 1.0); y2 = fmin(fmax(y2, 0.0), 1.0);

    ((float4*)boxes_out)[gi] = make_float4((float)x1, (float)y1, (float)x2, (float)y2);
    scores_out[gi] = (float)best;
    cls_out[gi]    = (float)ci;
}

// ---------------- kernel 1: f64 MFMA GEMM, 32 pos/wave, split-K=2, 4 w/SIMD --
// Block = 4 waves: wave wv -> positions n0+(wv>>1)*32..+31, K-half (wv&1)*256.
// Per wave: 64 K-steps x {2 A-loads + 2 B-loads + 4 MFMAs}. 4 blocks/CU =
// 16 waves/CU = 4 waves/SIMD: matrix pipe fed by cross-wave interleave
// (structural TLP; compiler-ILP attempts R9/R10 plateaued). 4-slot static
// circular buffer keeps a depth-3 prefetch on top.
// D row map self-calibrated (round-8-proven).
__global__ __launch_bounds__(256, 4) void k_main(const float* __restrict__ feat,
                                                 const double* __restrict__ wpad_g,
                                                 const double* __restrict__ b64,
                                                 float* __restrict__ boxes_out,
                                                 float* __restrict__ scores_out,
                                                 float* __restrict__ cls_out)
{
    __shared__ double red[64][33];                // 16896 B: reduce + epilogue
    const int b    = blockIdx.y;
    const int tid  = threadIdx.x;
    const int l    = tid & 63;
    const int wv   = tid >> 6;
    const int half = wv & 1;                      // K-half
    const int pg   = wv >> 1;                     // position-group 0/1
    const int n0   = blockIdx.x * 64 + pg * 32;
    const int cbase = half * 256;

    // --- runtime D-row calibration: A[m][0]=m, B[0][n]=1 => D[m][n]=m -------
    double ca = ((l >> 4) == 0) ? (double)(l & 15) : 0.0;
    double cb = ((l >> 4) == 0) ? 1.0 : 0.0;
    f64x4 cd = {0.0, 0.0, 0.0, 0.0};
    cd = __builtin_amdgcn_mfma_f64_16x16x4f64(ca, cb, cd, 0, 0, 0);
    int rmap[4];
#pragma unroll
    for (int v = 0; v < 4; ++v) {
        int r = (int)(cd[v] + 0.5);
        rmap[v] = (r < 0) ? 0 : (r > 15 ? 15 : r);
    }

    const float* __restrict__ fA =
        feat + ((size_t)b * 512 + cbase + (l >> 4)) * NPOS + n0 + (l & 15);
    const double* __restrict__ wB =
        wpad_g + ((size_t)(cbase + (l >> 4)) << 5) + (l & 15);

    f64x4 acc00 = {0.0, 0.0, 0.0, 0.0};   // frag0 x out0-15
    f64x4 acc01 = {0.0, 0.0, 0.0, 0.0};   // frag0 x out16-31
    f64x4 acc10 = {0.0, 0.0, 0.0, 0.0};   // frag1 x out0-15
    f64x4 acc11 = {0.0, 0.0, 0.0, 0.0};   // frag1 x out16-31

    // 4-slot circular buffers, all indices compile-time after unroll 4
    float  af0[4], af1[4];
    double bf0[4], bf1[4];
#pragma unroll
    for (int d = 0; d < 3; ++d) {                 // prologue: steps 0..2
        af0[d] = fA[(size_t)d * 4096];
        af1[d] = fA[(size_t)d * 4096 + 16];
        bf0[d] = wB[(size_t)d * 128];
        bf1[d] = wB[(size_t)d * 128 + 16];
    }

#pragma unroll 4
    for (int s = 0; s < 64; ++s) {
        const int slot  = s & 3;
        const int pslot = (s + 3) & 3;
        const int sp    = (s + 3) & 63;           // wraps at tail (dummy reloads)
        af0[pslot] = fA[(size_t)sp * 4096];
        af1[pslot] = fA[(size_t)sp * 4096 + 16];
        bf0[pslot] = wB[(size_t)sp * 128];
        bf1[pslot] = wB[(size_t)sp * 128 + 16];

        double av0 = (double)af0[slot];
        double av1 = (double)af1[slot];
        acc00 = __builtin_amdgcn_mfma_f64_16x16x4f64(av0, bf0[slot], acc00, 0, 0, 0);
        acc01 = __builtin_amdgcn_mfma_f64_16x16x4f64(av0, bf1[slot], acc01, 0, 0, 0);
        acc10 = __builtin_amdgcn_mfma_f64_16x16x4f64(av1, bf0[slot], acc10, 0, 0, 0);
        acc11 = __builtin_amdgcn_mfma_f64_16x16x4f64(av1, bf1[slot], acc11, 0, 0, 0);
    }

    // ---- deterministic split-K reduce via LDS: K-hi dumps, K-lo adds ----
    if (half == 1) {
#pragma unroll
        for (int v = 0; v < 4; ++v) {
            int r0 = pg * 32 + rmap[v];
            red[r0][(l & 15)]           = acc00[v];
            red[r0][(l & 15) + 16]      = acc01[v];
            red[r0 + 16][(l & 15)]      = acc10[v];
            red[r0 + 16][(l & 15) + 16] = acc11[v];
        }
    }
    __syncthreads();
    if (half == 0) {
#pragma unroll
        for (int v = 0; v < 4; ++v) {
            int r0 = pg * 32 + rmap[v];
            acc00[v] += red[r0][(l & 15)];
            acc01[v] += red[r0][(l & 15) + 16];
            acc10[v] += red[r0 + 16][(l & 15)];
            acc11[v] += red[r0 + 16][(l & 15) + 16];
        }
    }
    __syncthreads();
    if (half == 0) {
#pragma unroll
        for (int v = 0; v < 4; ++v) {
            int r0 = pg * 32 + rmap[v];
            red[r0][(l & 15)]           = acc00[v];
            red[r0][(l & 15) + 16]      = acc01[v];
            red[r0 + 16][(l & 15)]      = acc10[v];
            red[r0 + 16][(l & 15) + 16] = acc11[v];
        }
    }
    __syncthreads();

    if (tid < 64) {
        double acc[NOUT];
#pragma unroll
        for (int o = 0; o < NOUT; ++o) acc[o] = red[tid][o];
        int n = blockIdx.x * 64 + tid;
        epilogue(acc, b64, n, b * NPOS + n, boxes_out, scores_out, cls_out);
    }
}

// ---------------- kernel 2: per-batch bitonic sort (desc score, stable) -------
__global__ __launch_bounds__(256) void k_sort(const float* __restrict__ scores,
                                              const float* __restrict__ boxes,
                                              const float* __restrict__ cls,
                                              int* __restrict__ order,
                                              float4* __restrict__ sbox,
                                              int* __restrict__ scls,
                                              u64* __restrict__ validW)
{
    __shared__ u64 key[NPOS];
    __shared__ u64 vw[16];
    int b = blockIdx.x, tid = threadIdx.x;

    for (int ppos = tid; ppos < NPOS; ppos += 256) {
        u32 bits = __float_as_uint(scores[b * NPOS + ppos]);
        u32 d = ~(bits | 0x80000000u);   // descending-monotone key (scores >= 0)
        key[ppos] = ((u64)d << 32) | (u32)ppos;
    }
    if (tid < 16) vw[tid] = 0ull;
    __syncthreads();

    for (int k = 2; k <= NPOS; k <<= 1) {
        for (int j = k >> 1; j > 0; j >>= 1) {
            for (int idx = tid; idx < NPOS; idx += 256) {
                int l = idx ^ j;
                if (l > idx) {
                    u64 a = key[idx], c = key[l];
                    bool up = ((idx & k) == 0);
                    if ((a > c) == up) { key[idx] = c; key[l] = a; }
                }
            }
            __syncthreads();
        }
    }

    for (int ppos = tid; ppos < NPOS; ppos += 256) {
        u64 kk = key[ppos];
        int idx = (int)(kk & 0xffffffffu);
        order[b * NPOS + ppos] = idx;
        sbox [b * NPOS + ppos] = ((const float4*)boxes)[b * NPOS + idx];
        scls [b * NPOS + ppos] = (int)cls[b * NPOS + idx];
        u32 sb = (~(u32)(kk >> 32)) & 0x7fffffffu;
        float sc = __uint_as_float(sb);
        if (sc > 0.01f) atomicOr(&vw[ppos >> 6], 1ull << (ppos & 63));
    }
    __syncthreads();
    if (tid < 16) validW[b * 16 + tid] = vw[tid];
}

// ---------------- kernel 3: suppression mask, ballot style -------------------
__global__ __launch_bounds__(64) void k_mask(const float4* __restrict__ sbox,
                                             const int* __restrict__ scls,
                                             u64* __restrict__ masksT)
{
    __shared__ float4 boxl[256];
    __shared__ float2 acl[256];
    const int wc  = blockIdx.x;
    const int w   = wc >> 2, chunk = wc & 3;
    const int b   = blockIdx.y;
    const int lane = threadIdx.x;
    const int i0   = chunk * 256;
    const int imax = (w + 1) * 64;            // rows that can suppress into word w
    u64* __restrict__ mcol = masksT + (((size_t)b * 16 + w) << 10);

    const int jg = w * 64 + lane;
    float4 bj = sbox[b * NPOS + jg];
    float  aj = (bj.z - bj.x) * (bj.w - bj.y);
    int    cj = scls[b * NPOS + jg];

    int iend = imax - i0;                     // rows in this chunk needing compute
    if (iend > 256) iend = 256;

    if (iend > 0) {
        for (int i = lane; i < iend; i += 64) {
            float4 bb = sbox[b * NPOS + i0 + i];
            boxl[i] = bb;
            acl[i]  = make_float2((bb.z - bb.x) * (bb.w - bb.y),
                                  __int_as_float(scls[b * NPOS + i0 + i]));
        }
    }
    __syncthreads();

#pragma unroll 1
    for (int t = 0; t < 256; t += 64) {       // 64-row tiles
        u64 myword = 0ull;
        if (t < iend) {
#pragma unroll 1
            for (int s = 0; s < 64; s += 8) {
                u64 bits[8];
#pragma unroll
                for (int u = 0; u < 8; ++u) {
                    int i = t + s + u;
                    float4 bi = boxl[i];      // wave-uniform broadcast
                    float2 ac = acl[i];
                    float xx1 = fmaxf(bi.x, bj.x), yy1 = fmaxf(bi.y, bj.y);
                    float xx2 = fminf(bi.z, bj.z), yy2 = fminf(bi.w, bj.w);
                    float ww = fmaxf(1e-28f, xx2 - xx1);
                    float hh = fmaxf(1e-28f, yy2 - yy1);
                    float inter = ww * hh;
                    float uni = ac.x + aj - inter;
                    bool sup = (__float_as_int(ac.y) == cj) && (uni > 0.0f) &&
                               (inter > 0.5f * uni) && (jg > i0 + i) && (i < iend);
                    bits[u] = __ballot(sup);
                }
#pragma unroll
                for (int u = 0; u < 8; ++u)
                    myword = (lane == s + u) ? bits[u] : myword;
            }
        }
        mcol[i0 + t + lane] = myword;         // coalesced (row-major in word)
    }
}

// ---------------- kernel 4: sequential suppression scan + scatter keep --------
__global__ __launch_bounds__(64) void k_scan(const u64* __restrict__ validW,
                                             const u64* __restrict__ masksT,
                                             const int* __restrict__ order,
                                             float* __restrict__ keep_out)
{
    int b = blockIdx.x, lane = threadIdx.x;
    u64 keep = (lane < 16) ? validW[b * 16 + lane] : 0ull;
    const u64* M = masksT + ((size_t)b << 14);    // [16 words][1024 rows]
    int myrow = lane >> 4;
    int myw = lane & 15;

    u64 buf[8];
#pragma unroll
    for (int d = 0; d < 8; ++d)
        buf[d] = M[((size_t)myw << 10) + (d * 4 + myrow)];

    for (int g0 = 0; g0 < 256; g0 += 8) {
#pragma unroll
        for (int d = 0; d < 8; ++d) {
            int g = g0 + d;
            u64 cur = buf[d];
            int gp = g + 8;
            buf[d] = (gp < 256) ? M[((size_t)myw << 10) + (gp * 4 + myrow)] : 0ull;
            if (__any(cur != 0ull)) {
#pragma unroll
                for (int r = 0; r < 4; ++r) {
                    int i = g * 4 + r;
                    u64 kw = __shfl(keep, i >> 6);
                    if ((kw >> (i & 63)) & 1ull) {
                        u64 mm = __shfl(cur, r * 16 + myw);
                        if (lane < 16) keep &= ~mm;
                    }
                }
            }
        }
    }

#pragma unroll
    for (int t = 0; t < 16; ++t) {
        int ppos = t * 64 + lane;
        u64 kw = __shfl(keep, t);
        float v = ((kw >> lane) & 1ull) ? 1.0f : 0.0f;
        keep_out[b * NPOS + order[b * NPOS + ppos]] = v;
    }
}

// ------------------------------------------------------------------------------
extern "C" void kernel_launch(void* const* d_in, const int* in_sizes, int n_in,
                              void* d_out, int out_size, void* d_ws, size_t ws_size,
                              hipStream_t stream)
{
    const float* feat = (const float*)d_in[0];
    const float* w    = (const float*)d_in[1];
    const float* bias = (const float*)d_in[2];

    float* out = (float*)d_out;
    float* boxes_out  = out;
    float* scores_out = out + NB * NPOS * 4;
    float* cls_out    = out + NB * NPOS * 5;
    float* keep_out   = out + NB * NPOS * 6;

    char* ws = (char*)d_ws;
    double* wpad  = (double*)(ws + OFF_W64);
    double* b64   = (double*)(ws + OFF_B64);
    int*    order = (int*)   (ws + OFF_ORDER);
    float4* sbox  = (float4*)(ws + OFF_SBOX);
    int*    scls  = (int*)   (ws + OFF_SCLS);
    u64*    validW= (u64*)   (ws + OFF_VALID);
    u64*    masksT= (u64*)   (ws + OFF_MASK);

    hipLaunchKernelGGL(k_cvt,  dim3(64),     dim3(256), 0, stream, w, bias, wpad, b64);
    hipLaunchKernelGGL(k_main, dim3(16, 64), dim3(256), 0, stream, feat, wpad, b64,
                       boxes_out, scores_out, cls_out);
    hipLaunchKernelGGL(k_sort, dim3(64),     dim3(256), 0, stream, scores_out,
                       boxes_out, cls_out, order, sbox, scls, validW);
    hipLaunchKernelGGL(k_mask, dim3(64, 64), dim3(64),  0, stream, sbox, scls, masksT);
    hipLaunchKernelGGL(k_scan, dim3(64),     dim3(64),  0, stream, validW, masksT,
                       order, keep_out);
}

// Round 12
// 141.073 us; speedup vs baseline: 1.2153x; 1.0992x over previous
//
#include <hip/hip_runtime.h>
#include <hip/hip_bf16.h>

typedef unsigned long long u64;
typedef unsigned int u32;
typedef __attribute__((ext_vector_type(4))) double f64x4;

#define NB   64
#define NPOS 1024
#define NOUT 25
#define NCLS 20
#define WROW 32            // f64 weights per channel row, padded to 256 B

// ---- workspace layout (bytes) ----
#define OFF_W64   0          // double wpad[512*32] = 131072
#define OFF_B64   131072     // double b64[25]      = 200 (pad to 131328)
#define OFF_ORDER 131328     // int    order[64*1024]   = 262144
#define OFF_SBOX  393472     // float4 sbox[64*1024]    = 1048576
#define OFF_SCLS  1442048    // int    scls[64*1024]    = 262144
#define OFF_VALID 1704192    // u64    validW[64*16]    = 8192
#define OFF_MASK  1712384    // u64    masksT[64][16][1024] = 8388608
#define OFF_SUMM  10100992   // u32    summ32[64][16]   = 4096 -> end 10105088

// ---------------- kernel 0: weights -> f64, layout [c][32] (pad 0) -----------
__global__ __launch_bounds__(256) void k_cvt(const float* __restrict__ w,
                                             const float* __restrict__ bias,
                                             double* __restrict__ wpad,
                                             double* __restrict__ b64)
{
    int idx = blockIdx.x * 256 + threadIdx.x;
    if (idx < 512 * WROW) {
        int c = idx >> 5, o = idx & 31;
        wpad[idx] = (o < NOUT) ? (double)w[o * 512 + c] : 0.0;
    }
    if (idx < NOUT) b64[idx] = (double)bias[idx];
}

// ---------------- f64 epilogue: sigmoid/softmax/argmax + box decode ----------
__device__ __forceinline__ void epilogue(const double* __restrict__ acc,
                                         const double* __restrict__ b64,
                                         int n, int gi,
                                         float* __restrict__ boxes_out,
                                         float* __restrict__ scores_out,
                                         float* __restrict__ cls_out)
{
    double p[NOUT];
#pragma unroll
    for (int o = 0; o < NOUT; ++o) p[o] = acc[o] + b64[o];

    double conf = 1.0 / (1.0 + exp(-p[0]));
    double m = p[1]; int ci = 0;
#pragma unroll
    for (int i = 2; i <= NCLS; ++i) {
        if (p[i] > m) { m = p[i]; ci = i - 1; }
    }
    double ssum = 0.0;
#pragma unroll
    for (int i = 0; i < NCLS; ++i) ssum += exp(p[1 + i] - m);
    double best = conf / ssum;

    int gx = n & 31, gy = n >> 5;
    double sx = 1.0 / (1.0 + exp(-p[21]));
    double sy = 1.0 / (1.0 + exp(-p[22]));
    double cx = (sx + (double)gx) * 32.0;
    double cy = (sy + (double)gy) * 32.0;
    double bw = exp(p[23]), bh = exp(p[24]);
    double x1 = (cx - bw * 0.5) * (1.0 / 1024.0);
    double y1 = (cy - bh * 0.5) * (1.0 / 1024.0);
    double x2 = (cx + bw * 0.5) * (1.0 / 1024.0);
    double y2 = (cy + bh * 0.5) * (1.0 / 1024.0);
    x1 = fmin(fmax(x1, 0.0), 1.0); y1 = fmin(fmax(y1, 0.0), 1.0);
    x2 = fmin(fmax(x2, 0.0), 1.0); y2 = fmin(fmax(y2, 0.0), 1.0);

    ((float4*)boxes_out)[gi] = make_float4((float)x1, (float)y1, (float)x2, (float)y2);
    scores_out[gi] = (float)best;
    cls_out[gi]    = (float)ci;
}

// ---------------- kernel 1: f64 MFMA GEMM, LDS-staged, 16 B/lane loads -------
// Block 256 = 4 waves; tile 64 pos x 32 out x K=512 in 16 chunks of 32 ch.
// Staging: float4 (A) / double2 (B) per lane -> dbuf LDS; T14 split (issue
// loads early, ds_write after consume, 1 barrier/chunk). Wave wv: pos-half
// pg=wv>>1 (2 frags), out-half oh=wv&1. Per k-step: 2 ds_read_b32 +
// 1 ds_read_b64 + 2 MFMA. LDS 49.7 KB -> 3 blocks/CU (3 waves/SIMD).
// D row map self-calibrated (R8-proven).
__global__ __launch_bounds__(256, 3) void k_main(const float* __restrict__ feat,
                                                 const double* __restrict__ wpad_g,
                                                 const double* __restrict__ b64,
                                                 float* __restrict__ boxes_out,
                                                 float* __restrict__ scores_out,
                                                 float* __restrict__ cls_out)
{
    __shared__ __align__(16) float  Ab[2][32 * 64];   // 16384 B  [ch][pos]
    __shared__ __align__(16) double Bb[2][32 * 32];   // 16384 B  [ch][out]
    __shared__ double pd[64][33];                     // 16896 B  epilogue
    const int b   = blockIdx.y;
    const int tid = threadIdx.x;
    const int l   = tid & 63;
    const int wv  = tid >> 6;
    const int pg  = wv >> 1;          // position half (32 pos)
    const int oh  = wv & 1;           // out half (16 outs)
    const int n0  = blockIdx.x * 64;

    // --- runtime D-row calibration: A[m][0]=m, B[0][n]=1 => D[m][n]=m -------
    double ca = ((l >> 4) == 0) ? (double)(l & 15) : 0.0;
    double cb = ((l >> 4) == 0) ? 1.0 : 0.0;
    f64x4 cd = {0.0, 0.0, 0.0, 0.0};
    cd = __builtin_amdgcn_mfma_f64_16x16x4f64(ca, cb, cd, 0, 0, 0);
    int rmap[4];
#pragma unroll
    for (int v = 0; v < 4; ++v) {
        int r = (int)(cd[v] + 0.5);
        rmap[v] = (r < 0) ? 0 : (r > 15 ? 15 : r);
    }

    const float* __restrict__ featb = feat + (size_t)b * 512 * NPOS + n0;

#define A_SRC(C0, IT) (((const float4*)(featb + (size_t)((C0) + wv*8 + (IT)*4 + (l>>4)) * NPOS)) + (l & 15))
#define B_SRC(C0, IT) (((const double2*)(wpad_g + (size_t)((C0) + wv*8 + (IT)*4 + (l>>4)) * WROW)) + (l & 15))
#define A_DST(BUF, IT) ((float4*)(&Ab[BUF][(wv*8 + (IT)*4) * 64] + l*4))
#define B_DST(BUF, IT) ((double2*)(&Bb[BUF][(wv*8 + (IT)*4) * 32] + l*2))

    f64x4 acc0 = {0.0, 0.0, 0.0, 0.0};   // pos frag 0 (pg*32+0..15) x out-half
    f64x4 acc1 = {0.0, 0.0, 0.0, 0.0};   // pos frag 1 (pg*32+16..31)

    // prologue: stage chunk 0
    float4  ra0 = *A_SRC(0, 0), ra1 = *A_SRC(0, 1);
    double2 rb0 = *B_SRC(0, 0), rb1 = *B_SRC(0, 1);
    *A_DST(0, 0) = ra0;  *A_DST(0, 1) = ra1;
    *B_DST(0, 0) = rb0;  *B_DST(0, 1) = rb1;
    __syncthreads();

#pragma unroll 1
    for (int t = 0; t < 16; ++t) {
        const int buf = t & 1;
        const bool more = (t + 1) < 16;
        const int c1 = (t + 1) * 32;
        if (more) {                       // issue next-chunk loads (hide under MFMA)
            ra0 = *A_SRC(c1, 0);  ra1 = *A_SRC(c1, 1);
            rb0 = *B_SRC(c1, 0);  rb1 = *B_SRC(c1, 1);
        }
#pragma unroll
        for (int s = 0; s < 8; ++s) {     // 8 k-steps x 4 ch
            const int rowA = (4*s + (l >> 4)) * 64 + pg * 32 + (l & 15);
            const int rowB = (4*s + (l >> 4)) * 32 + oh * 16 + (l & 15);
            double av0 = (double)Ab[buf][rowA];
            double av1 = (double)Ab[buf][rowA + 16];
            double bv  = Bb[buf][rowB];
            acc0 = __builtin_amdgcn_mfma_f64_16x16x4f64(av0, bv, acc0, 0, 0, 0);
            acc1 = __builtin_amdgcn_mfma_f64_16x16x4f64(av1, bv, acc1, 0, 0, 0);
        }
        if (more) {                       // write next chunk into alt buffer
            *A_DST(buf ^ 1, 0) = ra0;  *A_DST(buf ^ 1, 1) = ra1;
            *B_DST(buf ^ 1, 0) = rb0;  *B_DST(buf ^ 1, 1) = rb1;
        }
        __syncthreads();
    }
#undef A_SRC
#undef B_SRC
#undef A_DST
#undef B_DST

    // dump D to LDS as [pos][out] with calibrated row map
#pragma unroll
    for (int v = 0; v < 4; ++v) {
        int r0 = pg * 32 + rmap[v];
        pd[r0][oh * 16 + (l & 15)]      = acc0[v];
        pd[r0 + 16][oh * 16 + (l & 15)] = acc1[v];
    }
    __syncthreads();

    if (tid < 64) {
        double acc[NOUT];
#pragma unroll
        for (int o = 0; o < NOUT; ++o) acc[o] = pd[tid][o];
        int n = n0 + tid;
        epilogue(acc, b64, n, b * NPOS + n, boxes_out, scores_out, cls_out);
    }
}

// ---------------- kernel 2: per-batch bitonic sort (desc score, stable) ------
// 512 thr; also zero-inits the suppression summary for k_mask.
__global__ __launch_bounds__(512) void k_sort(const float* __restrict__ scores,
                                              const float* __restrict__ boxes,
                                              const float* __restrict__ cls,
                                              int* __restrict__ order,
                                              float4* __restrict__ sbox,
                                              int* __restrict__ scls,
                                              u64* __restrict__ validW,
                                              u32* __restrict__ summ32)
{
    __shared__ u64 key[NPOS];
    __shared__ u64 vw[16];
    int b = blockIdx.x, tid = threadIdx.x;

    for (int ppos = tid; ppos < NPOS; ppos += 512) {
        u32 bits = __float_as_uint(scores[b * NPOS + ppos]);
        u32 d = ~(bits | 0x80000000u);   // descending-monotone key (scores >= 0)
        key[ppos] = ((u64)d << 32) | (u32)ppos;
    }
    if (tid < 16) { vw[tid] = 0ull; summ32[b * 16 + tid] = 0u; }
    __syncthreads();

    for (int k = 2; k <= NPOS; k <<= 1) {
        for (int j = k >> 1; j > 0; j >>= 1) {
            for (int idx = tid; idx < NPOS; idx += 512) {
                int l = idx ^ j;
                if (l > idx) {
                    u64 a = key[idx], c = key[l];
                    bool up = ((idx & k) == 0);
                    if ((a > c) == up) { key[idx] = c; key[l] = a; }
                }
            }
            __syncthreads();
        }
    }

    for (int ppos = tid; ppos < NPOS; ppos += 512) {
        u64 kk = key[ppos];
        int idx = (int)(kk & 0xffffffffu);
        order[b * NPOS + ppos] = idx;
        sbox [b * NPOS + ppos] = ((const float4*)boxes)[b * NPOS + idx];
        scls [b * NPOS + ppos] = (int)cls[b * NPOS + idx];
        u32 sb = (~(u32)(kk >> 32)) & 0x7fffffffu;
        float sc = __uint_as_float(sb);
        if (sc > 0.01f) atomicOr(&vw[ppos >> 6], 1ull << (ppos & 63));
    }
    __syncthreads();
    if (tid < 16) validW[b * 16 + tid] = vw[tid];
}

// ---------------- kernel 3: suppression mask, ballot + sparse store ----------
// Stores a 64-row mask tile ONLY if nonzero; flags it in summ32[b][grp] bit w.
// Unflagged tiles are never read by k_scan (stale ws contents are harmless).
__global__ __launch_bounds__(64) void k_mask(const float4* __restrict__ sbox,
                                             const int* __restrict__ scls,
                                             u64* __restrict__ masksT,
                                             u32* __restrict__ summ32)
{
    __shared__ float4 boxl[256];
    __shared__ float2 acl[256];
    const int wc  = blockIdx.x;
    const int w   = wc >> 2, chunk = wc & 3;
    const int b   = blockIdx.y;
    const int lane = threadIdx.x;
    const int i0   = chunk * 256;
    const int imax = (w + 1) * 64;            // rows that can suppress into word w
    u64* __restrict__ mcol = masksT + (((size_t)b * 16 + w) << 10);

    const int jg = w * 64 + lane;
    float4 bj = sbox[b * NPOS + jg];
    float  aj = (bj.z - bj.x) * (bj.w - bj.y);
    int    cj = scls[b * NPOS + jg];

    int iend = imax - i0;
    if (iend > 256) iend = 256;
    if (iend <= 0) return;                    // whole chunk above diagonal

    for (int i = lane; i < iend; i += 64) {
        float4 bb = sbox[b * NPOS + i0 + i];
        boxl[i] = bb;
        acl[i]  = make_float2((bb.z - bb.x) * (bb.w - bb.y),
                              __int_as_float(scls[b * NPOS + i0 + i]));
    }
    __syncthreads();

#pragma unroll 1
    for (int t = 0; t < 256; t += 64) {       // 64-row tiles (= summary granule)
        if (t >= iend) break;
        u64 myword = 0ull;
#pragma unroll 1
        for (int s = 0; s < 64; s += 8) {
            u64 bits[8];
#pragma unroll
            for (int u = 0; u < 8; ++u) {
                int i = t + s + u;
                float4 bi = boxl[i];          // wave-uniform broadcast
                float2 ac = acl[i];
                float xx1 = fmaxf(bi.x, bj.x), yy1 = fmaxf(bi.y, bj.y);
                float xx2 = fminf(bi.z, bj.z), yy2 = fminf(bi.w, bj.w);
                float ww = fmaxf(1e-28f, xx2 - xx1);
                float hh = fmaxf(1e-28f, yy2 - yy1);
                float inter = ww * hh;
                float uni = ac.x + aj - inter;
                bool sup = (__float_as_int(ac.y) == cj) && (uni > 0.0f) &&
                           (inter > 0.5f * uni) && (jg > i0 + i) && (i < iend);
                bits[u] = __ballot(sup);
            }
#pragma unroll
            for (int u = 0; u < 8; ++u)
                myword = (lane == s + u) ? bits[u] : myword;
        }
        bool nz = __any(myword != 0ull);
        if (nz) {
            mcol[i0 + t + lane] = myword;
            if (lane == 0)
                atomicOr(&summ32[b * 16 + ((i0 + t) >> 6)], 1u << w);
        }
    }
}

// ---------------- kernel 4: summary-driven suppression scan ------------------
__global__ __launch_bounds__(64) void k_scan(const u64* __restrict__ validW,
                                             const u64* __restrict__ masksT,
                                             const u32* __restrict__ summ32,
                                             const int* __restrict__ order,
                                             float* __restrict__ keep_out)
{
    int b = blockIdx.x, lane = threadIdx.x;
    u64 keep = (lane < 16) ? validW[b * 16 + lane] : 0ull;
    u32 sv   = (lane < 16) ? summ32[b * 16 + lane] : 0u;
    const u64* M = masksT + ((size_t)b << 14);    // [16 words][1024 rows]
    int myrow = lane >> 4;
    int myw   = lane & 15;

#pragma unroll 1
    for (int G = 0; G < 16; ++G) {                // 64-row groups
        u32 gm = (u32)__shfl((int)sv, G);         // word-flags for this group
        if (gm == 0u) continue;                   // no suppressor rows here
#pragma unroll 1
        for (int g4 = 0; g4 < 16; ++g4) {         // 4-row subgroups
            u64 cur = 0ull;
            if ((gm >> myw) & 1u)
                cur = M[((size_t)myw << 10) + G * 64 + g4 * 4 + myrow];
            if (__any(cur != 0ull)) {
#pragma unroll
                for (int r = 0; r < 4; ++r) {
                    int i = G * 64 + g4 * 4 + r;
                    u64 kw = __shfl(keep, i >> 6);
                    if ((kw >> (i & 63)) & 1ull) {
                        u64 mm = __shfl(cur, r * 16 + myw);
                        if (lane < 16) keep &= ~mm;
                    }
                }
            }
        }
    }

#pragma unroll
    for (int t = 0; t < 16; ++t) {
        int ppos = t * 64 + lane;
        u64 kw = __shfl(keep, t);
        float v = ((kw >> lane) & 1ull) ? 1.0f : 0.0f;
        keep_out[b * NPOS + order[b * NPOS + ppos]] = v;
    }
}

// ------------------------------------------------------------------------------
extern "C" void kernel_launch(void* const* d_in, const int* in_sizes, int n_in,
                              void* d_out, int out_size, void* d_ws, size_t ws_size,
                              hipStream_t stream)
{
    const float* feat = (const float*)d_in[0];
    const float* w    = (const float*)d_in[1];
    const float* bias = (const float*)d_in[2];

    float* out = (float*)d_out;
    float* boxes_out  = out;
    float* scores_out = out + NB * NPOS * 4;
    float* cls_out    = out + NB * NPOS * 5;
    float* keep_out   = out + NB * NPOS * 6;

    char* ws = (char*)d_ws;
    double* wpad  = (double*)(ws + OFF_W64);
    double* b64   = (double*)(ws + OFF_B64);
    int*    order = (int*)   (ws + OFF_ORDER);
    float4* sbox  = (float4*)(ws + OFF_SBOX);
    int*    scls  = (int*)   (ws + OFF_SCLS);
    u64*    validW= (u64*)   (ws + OFF_VALID);
    u64*    masksT= (u64*)   (ws + OFF_MASK);
    u32*    summ32= (u32*)   (ws + OFF_SUMM);

    hipLaunchKernelGGL(k_cvt,  dim3(64),     dim3(256), 0, stream, w, bias, wpad, b64);
    hipLaunchKernelGGL(k_main, dim3(16, 64), dim3(256), 0, stream, feat, wpad, b64,
                       boxes_out, scores_out, cls_out);
    hipLaunchKernelGGL(k_sort, dim3(64),     dim3(512), 0, stream, scores_out,
                       boxes_out, cls_out, order, sbox, scls, validW, summ32);
    hipLaunchKernelGGL(k_mask, dim3(64, 64), dim3(64),  0, stream, sbox, scls,
                       masksT, summ32);
    hipLaunchKernelGGL(k_scan, dim3(64),     dim3(64),  0, stream, validW, masksT,
                       summ32, order, keep_out);
}

// Round 13
// 128.431 us; speedup vs baseline: 1.3349x; 1.0984x over previous
//
#include <hip/hip_runtime.h>
#include <hip/hip_bf16.h>

typedef unsigned long long u64;
typedef unsigned int u32;
typedef __attribute__((ext_vector_type(4))) double f64x4;

#define NB   64
#define NPOS 1024
#define NOUT 25
#define NCLS 20
#define WROW 32            // f64 weights per channel row, padded to 256 B

// ---- workspace layout (bytes) ----
#define OFF_W64   0          // double wpad[512*32] = 131072
#define OFF_B64   131072     // double b64[25]      = 200 (pad to 131328)
#define OFF_ORDER 131328     // int    order[64*1024]   = 262144
#define OFF_SBOX  393472     // float4 sbox[64*1024]    = 1048576
#define OFF_SCLS  1442048    // int    scls[64*1024]    = 262144
#define OFF_VALID 1704192    // u64    validW[64*16]    = 8192
#define OFF_MASK  1712384    // u64    masksT[64][16][1024] = 8388608
#define OFF_SUMM  10100992   // u32    summ32[64][16]   = 4096 -> end 10105088

// ---------------- kernel 0: weights -> f64, layout [c][32] (pad 0) -----------
__global__ __launch_bounds__(256) void k_cvt(const float* __restrict__ w,
                                             const float* __restrict__ bias,
                                             double* __restrict__ wpad,
                                             double* __restrict__ b64)
{
    int idx = blockIdx.x * 256 + threadIdx.x;
    if (idx < 512 * WROW) {
        int c = idx >> 5, o = idx & 31;
        wpad[idx] = (o < NOUT) ? (double)w[o * 512 + c] : 0.0;
    }
    if (idx < NOUT) b64[idx] = (double)bias[idx];
}

// ---------------- f64 epilogue: sigmoid/softmax/argmax + box decode ----------
__device__ __forceinline__ void epilogue(const double* __restrict__ acc,
                                         const double* __restrict__ b64,
                                         int n, int gi,
                                         float* __restrict__ boxes_out,
                                         float* __restrict__ scores_out,
                                         float* __restrict__ cls_out)
{
    double p[NOUT];
#pragma unroll
    for (int o = 0; o < NOUT; ++o) p[o] = acc[o] + b64[o];

    double conf = 1.0 / (1.0 + exp(-p[0]));
    double m = p[1]; int ci = 0;
#pragma unroll
    for (int i = 2; i <= NCLS; ++i) {
        if (p[i] > m) { m = p[i]; ci = i - 1; }
    }
    double ssum = 0.0;
#pragma unroll
    for (int i = 0; i < NCLS; ++i) ssum += exp(p[1 + i] - m);
    double best = conf / ssum;

    int gx = n & 31, gy = n >> 5;
    double sx = 1.0 / (1.0 + exp(-p[21]));
    double sy = 1.0 / (1.0 + exp(-p[22]));
    double cx = (sx + (double)gx) * 32.0;
    double cy = (sy + (double)gy) * 32.0;
    double bw = exp(p[23]), bh = exp(p[24]);
    double x1 = (cx - bw * 0.5) * (1.0 / 1024.0);
    double y1 = (cy - bh * 0.5) * (1.0 / 1024.0);
    double x2 = (cx + bw * 0.5) * (1.0 / 1024.0);
    double y2 = (cy + bh * 0.5) * (1.0 / 1024.0);
    x1 = fmin(fmax(x1, 0.0), 1.0); y1 = fmin(fmax(y1, 0.0), 1.0);
    x2 = fmin(fmax(x2, 0.0), 1.0); y2 = fmin(fmax(y2, 0.0), 1.0);

    ((float4*)boxes_out)[gi] = make_float4((float)x1, (float)y1, (float)x2, (float)y2);
    scores_out[gi] = (float)best;
    cls_out[gi]    = (float)ci;
}

// ---------------- kernel 1: f64 MFMA GEMM, LDS-staged, pd unioned -----------
// Block 256 = 4 waves; tile 64 pos x 32 out x K=512 in 16 chunks of 32 ch.
// LDS: staging Ab(16K)+Bb(16K) = 32768 B; epilogue pd REUSES the same region
// (chunk-loop's final barrier separates). 32.8 KB -> 4 blocks/CU = 4 w/SIMD:
// per chunk each SIMD issues 4x16 dense f64 MFMAs (4096 cyc) vs ~300 cyc
// stage/barrier -> MfmaUtil ~85%+. D row map self-calibrated (R8-proven).
__global__ __launch_bounds__(256, 4) void k_main(const float* __restrict__ feat,
                                                 const double* __restrict__ wpad_g,
                                                 const double* __restrict__ b64,
                                                 float* __restrict__ boxes_out,
                                                 float* __restrict__ scores_out,
                                                 float* __restrict__ cls_out)
{
    __shared__ __align__(16) char smem[32768];
    float*  AbF = (float*)smem;                    // [2][32*64] floats
    double* BbF = (double*)(smem + 16384);         // [2][32*32] doubles
    double (*pd)[33] = (double(*)[33])smem;        // [64][33], post-loop reuse

    const int b   = blockIdx.y;
    const int tid = threadIdx.x;
    const int l   = tid & 63;
    const int wv  = tid >> 6;
    const int pg  = wv >> 1;          // position half (32 pos)
    const int oh  = wv & 1;           // out half (16 outs)
    const int n0  = blockIdx.x * 64;

    // --- runtime D-row calibration: A[m][0]=m, B[0][n]=1 => D[m][n]=m -------
    double ca = ((l >> 4) == 0) ? (double)(l & 15) : 0.0;
    double cb = ((l >> 4) == 0) ? 1.0 : 0.0;
    f64x4 cd = {0.0, 0.0, 0.0, 0.0};
    cd = __builtin_amdgcn_mfma_f64_16x16x4f64(ca, cb, cd, 0, 0, 0);
    int rmap[4];
#pragma unroll
    for (int v = 0; v < 4; ++v) {
        int r = (int)(cd[v] + 0.5);
        rmap[v] = (r < 0) ? 0 : (r > 15 ? 15 : r);
    }

    const float* __restrict__ featb = feat + (size_t)b * 512 * NPOS + n0;

#define A_SRC(C0, IT) (((const float4*)(featb + (size_t)((C0) + wv*8 + (IT)*4 + (l>>4)) * NPOS)) + (l & 15))
#define B_SRC(C0, IT) (((const double2*)(wpad_g + (size_t)((C0) + wv*8 + (IT)*4 + (l>>4)) * WROW)) + (l & 15))
#define A_DST(BUF, IT) ((float4*)(AbF + (BUF)*2048 + (wv*8 + (IT)*4) * 64 + l*4))
#define B_DST(BUF, IT) ((double2*)(BbF + (BUF)*1024 + (wv*8 + (IT)*4) * 32 + l*2))

    f64x4 acc0 = {0.0, 0.0, 0.0, 0.0};   // pos frag 0 (pg*32+0..15) x out-half
    f64x4 acc1 = {0.0, 0.0, 0.0, 0.0};   // pos frag 1 (pg*32+16..31)

    // prologue: stage chunk 0
    float4  ra0 = *A_SRC(0, 0), ra1 = *A_SRC(0, 1);
    double2 rb0 = *B_SRC(0, 0), rb1 = *B_SRC(0, 1);
    *A_DST(0, 0) = ra0;  *A_DST(0, 1) = ra1;
    *B_DST(0, 0) = rb0;  *B_DST(0, 1) = rb1;
    __syncthreads();

#pragma unroll 1
    for (int t = 0; t < 16; ++t) {
        const int buf = t & 1;
        const bool more = (t + 1) < 16;
        const int c1 = (t + 1) * 32;
        if (more) {                       // issue next-chunk loads (hide under MFMA)
            ra0 = *A_SRC(c1, 0);  ra1 = *A_SRC(c1, 1);
            rb0 = *B_SRC(c1, 0);  rb1 = *B_SRC(c1, 1);
        }
#pragma unroll
        for (int s = 0; s < 8; ++s) {     // 8 k-steps x 4 ch
            const int rowA = buf*2048 + (4*s + (l >> 4)) * 64 + pg * 32 + (l & 15);
            const int rowB = buf*1024 + (4*s + (l >> 4)) * 32 + oh * 16 + (l & 15);
            double av0 = (double)AbF[rowA];
            double av1 = (double)AbF[rowA + 16];
            double bv  = BbF[rowB];
            acc0 = __builtin_amdgcn_mfma_f64_16x16x4f64(av0, bv, acc0, 0, 0, 0);
            acc1 = __builtin_amdgcn_mfma_f64_16x16x4f64(av1, bv, acc1, 0, 0, 0);
        }
        if (more) {                       // write next chunk into alt buffer
            *A_DST(buf ^ 1, 0) = ra0;  *A_DST(buf ^ 1, 1) = ra1;
            *B_DST(buf ^ 1, 0) = rb0;  *B_DST(buf ^ 1, 1) = rb1;
        }
        __syncthreads();
    }
#undef A_SRC
#undef B_SRC
#undef A_DST
#undef B_DST

    // dump D to LDS as [pos][out] with calibrated row map (smem reused)
#pragma unroll
    for (int v = 0; v < 4; ++v) {
        int r0 = pg * 32 + rmap[v];
        pd[r0][oh * 16 + (l & 15)]      = acc0[v];
        pd[r0 + 16][oh * 16 + (l & 15)] = acc1[v];
    }
    __syncthreads();

    if (tid < 64) {
        double acc[NOUT];
#pragma unroll
        for (int o = 0; o < NOUT; ++o) acc[o] = pd[tid][o];
        int n = n0 + tid;
        epilogue(acc, b64, n, b * NPOS + n, boxes_out, scores_out, cls_out);
    }
}

// ---------------- kernel 2: per-batch bitonic sort (desc score, stable) ------
__global__ __launch_bounds__(512) void k_sort(const float* __restrict__ scores,
                                              const float* __restrict__ boxes,
                                              const float* __restrict__ cls,
                                              int* __restrict__ order,
                                              float4* __restrict__ sbox,
                                              int* __restrict__ scls,
                                              u64* __restrict__ validW,
                                              u32* __restrict__ summ32)
{
    __shared__ u64 key[NPOS];
    __shared__ u64 vw[16];
    int b = blockIdx.x, tid = threadIdx.x;

    for (int ppos = tid; ppos < NPOS; ppos += 512) {
        u32 bits = __float_as_uint(scores[b * NPOS + ppos]);
        u32 d = ~(bits | 0x80000000u);   // descending-monotone key (scores >= 0)
        key[ppos] = ((u64)d << 32) | (u32)ppos;
    }
    if (tid < 16) { vw[tid] = 0ull; summ32[b * 16 + tid] = 0u; }
    __syncthreads();

    for (int k = 2; k <= NPOS; k <<= 1) {
        for (int j = k >> 1; j > 0; j >>= 1) {
            for (int idx = tid; idx < NPOS; idx += 512) {
                int l = idx ^ j;
                if (l > idx) {
                    u64 a = key[idx], c = key[l];
                    bool up = ((idx & k) == 0);
                    if ((a > c) == up) { key[idx] = c; key[l] = a; }
                }
            }
            __syncthreads();
        }
    }

    for (int ppos = tid; ppos < NPOS; ppos += 512) {
        u64 kk = key[ppos];
        int idx = (int)(kk & 0xffffffffu);
        order[b * NPOS + ppos] = idx;
        sbox [b * NPOS + ppos] = ((const float4*)boxes)[b * NPOS + idx];
        scls [b * NPOS + ppos] = (int)cls[b * NPOS + idx];
        u32 sb = (~(u32)(kk >> 32)) & 0x7fffffffu;
        float sc = __uint_as_float(sb);
        if (sc > 0.01f) atomicOr(&vw[ppos >> 6], 1ull << (ppos & 63));
    }
    __syncthreads();
    if (tid < 16) validW[b * 16 + tid] = vw[tid];
}

// ---------------- kernel 3: suppression mask, ballot + sparse store ----------
__global__ __launch_bounds__(64) void k_mask(const float4* __restrict__ sbox,
                                             const int* __restrict__ scls,
                                             u64* __restrict__ masksT,
                                             u32* __restrict__ summ32)
{
    __shared__ float4 boxl[256];
    __shared__ float2 acl[256];
    const int wc  = blockIdx.x;
    const int w   = wc >> 2, chunk = wc & 3;
    const int b   = blockIdx.y;
    const int lane = threadIdx.x;
    const int i0   = chunk * 256;
    const int imax = (w + 1) * 64;            // rows that can suppress into word w
    u64* __restrict__ mcol = masksT + (((size_t)b * 16 + w) << 10);

    const int jg = w * 64 + lane;
    float4 bj = sbox[b * NPOS + jg];
    float  aj = (bj.z - bj.x) * (bj.w - bj.y);
    int    cj = scls[b * NPOS + jg];

    int iend = imax - i0;
    if (iend > 256) iend = 256;
    if (iend <= 0) return;                    // whole chunk above diagonal

    for (int i = lane; i < iend; i += 64) {
        float4 bb = sbox[b * NPOS + i0 + i];
        boxl[i] = bb;
        acl[i]  = make_float2((bb.z - bb.x) * (bb.w - bb.y),
                              __int_as_float(scls[b * NPOS + i0 + i]));
    }
    __syncthreads();

#pragma unroll 1
    for (int t = 0; t < 256; t += 64) {       // 64-row tiles (= summary granule)
        if (t >= iend) break;
        u64 myword = 0ull;
#pragma unroll 1
        for (int s = 0; s < 64; s += 8) {
            u64 bits[8];
#pragma unroll
            for (int u = 0; u < 8; ++u) {
                int i = t + s + u;
                float4 bi = boxl[i];          // wave-uniform broadcast
                float2 ac = acl[i];
                float xx1 = fmaxf(bi.x, bj.x), yy1 = fmaxf(bi.y, bj.y);
                float xx2 = fminf(bi.z, bj.z), yy2 = fminf(bi.w, bj.w);
                float ww = fmaxf(1e-28f, xx2 - xx1);
                float hh = fmaxf(1e-28f, yy2 - yy1);
                float inter = ww * hh;
                float uni = ac.x + aj - inter;
                bool sup = (__float_as_int(ac.y) == cj) && (uni > 0.0f) &&
                           (inter > 0.5f * uni) && (jg > i0 + i) && (i < iend);
                bits[u] = __ballot(sup);
            }
#pragma unroll
            for (int u = 0; u < 8; ++u)
                myword = (lane == s + u) ? bits[u] : myword;
        }
        bool nz = __any(myword != 0ull);
        if (nz) {
            mcol[i0 + t + lane] = myword;
            if (lane == 0)
                atomicOr(&summ32[b * 16 + ((i0 + t) >> 6)], 1u << w);
        }
    }
}

// ---------------- kernel 4: summary-driven suppression scan ------------------
__global__ __launch_bounds__(64) void k_scan(const u64* __restrict__ validW,
                                             const u64* __restrict__ masksT,
                                             const u32* __restrict__ summ32,
                                             const int* __restrict__ order,
                                             float* __restrict__ keep_out)
{
    int b = blockIdx.x, lane = threadIdx.x;
    u64 keep = (lane < 16) ? validW[b * 16 + lane] : 0ull;
    u32 sv   = (lane < 16) ? summ32[b * 16 + lane] : 0u;
    const u64* M = masksT + ((size_t)b << 14);    // [16 words][1024 rows]
    int myrow = lane >> 4;
    int myw   = lane & 15;

#pragma unroll 1
    for (int G = 0; G < 16; ++G) {                // 64-row groups
        u32 gm = (u32)__shfl((int)sv, G);         // word-flags for this group
        if (gm == 0u) continue;                   // no suppressor rows here
#pragma unroll 1
        for (int g4 = 0; g4 < 16; ++g4) {         // 4-row subgroups
            u64 cur = 0ull;
            if ((gm >> myw) & 1u)
                cur = M[((size_t)myw << 10) + G * 64 + g4 * 4 + myrow];
            if (__any(cur != 0ull)) {
#pragma unroll
                for (int r = 0; r < 4; ++r) {
                    int i = G * 64 + g4 * 4 + r;
                    u64 kw = __shfl(keep, i >> 6);
                    if ((kw >> (i & 63)) & 1ull) {
                        u64 mm = __shfl(cur, r * 16 + myw);
                        if (lane < 16) keep &= ~mm;
                    }
                }
            }
        }
    }

#pragma unroll
    for (int t = 0; t < 16; ++t) {
        int ppos = t * 64 + lane;
        u64 kw = __shfl(keep, t);
        float v = ((kw >> lane) & 1ull) ? 1.0f : 0.0f;
        keep_out[b * NPOS + order[b * NPOS + ppos]] = v;
    }
}

// ------------------------------------------------------------------------------
extern "C" void kernel_launch(void* const* d_in, const int* in_sizes, int n_in,
                              void* d_out, int out_size, void* d_ws, size_t ws_size,
                              hipStream_t stream)
{
    const float* feat = (const float*)d_in[0];
    const float* w    = (const float*)d_in[1];
    const float* bias = (const float*)d_in[2];

    float* out = (float*)d_out;
    float* boxes_out  = out;
    float* scores_out = out + NB * NPOS * 4;
    float* cls_out    = out + NB * NPOS * 5;
    float* keep_out   = out + NB * NPOS * 6;

    char* ws = (char*)d_ws;
    double* wpad  = (double*)(ws + OFF_W64);
    double* b64   = (double*)(ws + OFF_B64);
    int*    order = (int*)   (ws + OFF_ORDER);
    float4* sbox  = (float4*)(ws + OFF_SBOX);
    int*    scls  = (int*)   (ws + OFF_SCLS);
    u64*    validW= (u64*)   (ws + OFF_VALID);
    u64*    masksT= (u64*)   (ws + OFF_MASK);
    u32*    summ32= (u32*)   (ws + OFF_SUMM);

    hipLaunchKernelGGL(k_cvt,  dim3(64),     dim3(256), 0, stream, w, bias, wpad, b64);
    hipLaunchKernelGGL(k_main, dim3(16, 64), dim3(256), 0, stream, feat, wpad, b64,
                       boxes_out, scores_out, cls_out);
    hipLaunchKernelGGL(k_sort, dim3(64),     dim3(512), 0, stream, scores_out,
                       boxes_out, cls_out, order, sbox, scls, validW, summ32);
    hipLaunchKernelGGL(k_mask, dim3(64, 64), dim3(64),  0, stream, sbox, scls,
                       masksT, summ32);
    hipLaunchKernelGGL(k_scan, dim3(64),     dim3(64),  0, stream, validW, masksT,
                       summ32, order, keep_out);
}